// Round 1
// baseline (529.213 us; speedup 1.0000x reference)
//
#include <hip/hip_runtime.h>
#include <cstdint>

typedef __bf16 bf16;
typedef __bf16 bf16x8 __attribute__((ext_vector_type(8)));
typedef __bf16 bf16x4 __attribute__((ext_vector_type(4)));
typedef float  f32x4  __attribute__((ext_vector_type(4)));

#define DIM   1024
#define LSEQ  2048
#define NH    16
#define HD    64
#define NTOK  4096

// address-space casts via integer detour (flat->LDS offset is the low 32 bits on gfx9+)
#define AS1C(p) ((const __attribute__((address_space(1))) void*)(unsigned long long)(uintptr_t)(p))
#define AS3P(p) ((__attribute__((address_space(3))) void*)(unsigned int)(uintptr_t)(p))

__device__ __forceinline__ f32x4 mfma16(bf16x8 a, bf16x8 b, f32x4 c) {
  return __builtin_amdgcn_mfma_f32_16x16x32_bf16(a, b, c, 0, 0, 0);
}

// ---------------- x (fp32) -> bf16 ----------------
__global__ __launch_bounds__(256) void k_cvt(const float* __restrict__ x,
                                             bf16* __restrict__ xb) {
  const int i = (blockIdx.x * 256 + threadIdx.x) * 4;
  const f32x4 v = *(const f32x4*)(x + i);
  bf16x4 o;
  o[0] = (bf16)v[0]; o[1] = (bf16)v[1]; o[2] = (bf16)v[2]; o[3] = (bf16)v[3];
  *(bf16x4*)(xb + i) = o;
}

// ---------------- W_eff[o][d] = W[o][d] + 0.5 * sum_r A[d][r] * B[r][o] ----------------
struct WeffArgs {
  const float* W[4]; const float* A[4]; const float* B[4]; bf16* out[4];
};

__global__ __launch_bounds__(256) void k_weff(WeffArgs args) {
  const int o = blockIdx.x;
  const int z = blockIdx.y;
  const float* __restrict__ W  = args.W[z];
  const float* __restrict__ A  = args.A[z];
  const float* __restrict__ Bm = args.B[z];
  bf16* __restrict__ out = args.out[z];
  float Bo[16];
#pragma unroll
  for (int r = 0; r < 16; ++r) Bo[r] = Bm[r * DIM + o];
#pragma unroll
  for (int j = 0; j < 4; ++j) {
    const int d = j * 256 + (int)threadIdx.x;
    const float* Ar = A + (size_t)d * 16;
    float acc = 0.f;
#pragma unroll
    for (int r = 0; r < 16; ++r) acc += Ar[r] * Bo[r];
    out[(size_t)o * DIM + d] = (bf16)(W[(size_t)o * DIM + d] + 0.5f * acc);
  }
}

// ---------------- GEMM: out[i][o] = (sum_d X[i][d]*W[o][d] + bias[o]) * scale ----------------
// m97 structure: 128x128 tile, BK=32, 4 waves (2x2), global_load_lds width 16.
template <bool F32OUT>
__device__ __forceinline__ void gemm_body(const bf16* __restrict__ X,
                                          const bf16* __restrict__ W,
                                          const float* __restrict__ bias,
                                          void* __restrict__ out,
                                          float scale, int m0, int n0) {
  __shared__ __align__(16) bf16 As[128 * 32];
  __shared__ __align__(16) bf16 Bs[128 * 32];
  const int tid  = threadIdx.x;
  const int lane = tid & 63, w = tid >> 6;
  const int l15 = lane & 15, l4 = lane >> 4;
  const int wr = w >> 1, wc = w & 1;
  const int srow = w * 16 + (lane >> 2);   // staging row within 64-row half
  const int scol = (lane & 3) * 8;         // staging col (8 bf16 = 16B)

  f32x4 acc[4][4] = {};
  const bf16* ag = X + (size_t)m0 * DIM;
  const bf16* bg = W + (size_t)n0 * DIM;

  for (int kt = 0; kt < DIM / 32; ++kt) {
    const int k0 = kt * 32;
#pragma unroll
    for (int j = 0; j < 2; ++j) {
      const int row = j * 64 + srow;
      __builtin_amdgcn_global_load_lds(AS1C(ag + (size_t)row * DIM + k0 + scol),
                                       AS3P(As + (j * 64 + w * 16) * 32), 16, 0, 0);
      __builtin_amdgcn_global_load_lds(AS1C(bg + (size_t)row * DIM + k0 + scol),
                                       AS3P(Bs + (j * 64 + w * 16) * 32), 16, 0, 0);
    }
    __syncthreads();
    bf16x8 af[4], bfr[4];
#pragma unroll
    for (int m = 0; m < 4; ++m)
      af[m] = *(const bf16x8*)(As + (wr * 64 + m * 16 + l15) * 32 + l4 * 8);
#pragma unroll
    for (int n = 0; n < 4; ++n)
      bfr[n] = *(const bf16x8*)(Bs + (wc * 64 + n * 16 + l15) * 32 + l4 * 8);
#pragma unroll
    for (int m = 0; m < 4; ++m)
#pragma unroll
      for (int n = 0; n < 4; ++n)
        acc[m][n] = mfma16(af[m], bfr[n], acc[m][n]);
    __syncthreads();
  }

#pragma unroll
  for (int m = 0; m < 4; ++m) {
    const int r0 = m0 + wr * 64 + m * 16 + l4 * 4;
#pragma unroll
    for (int n = 0; n < 4; ++n) {
      const int c = n0 + wc * 64 + n * 16 + l15;
      const float bc = bias[c];
#pragma unroll
      for (int t = 0; t < 4; ++t) {
        const float y = (acc[m][n][t] + bc) * scale;
        if constexpr (F32OUT)
          ((float*)out)[(size_t)(r0 + t) * DIM + c] = y;
        else
          ((bf16*)out)[(size_t)(r0 + t) * DIM + c] = (bf16)y;
      }
    }
  }
}

__global__ __launch_bounds__(256) void k_gemm_qkv(
    const bf16* __restrict__ xb, const bf16* __restrict__ weff,
    const float* __restrict__ bq, const float* __restrict__ bk,
    const float* __restrict__ bv,
    bf16* __restrict__ q, bf16* __restrict__ k, bf16* __restrict__ v) {
  const int z = blockIdx.z;
  const bf16* W = weff + (size_t)z * DIM * DIM;
  const float* bias = (z == 0) ? bq : (z == 1) ? bk : bv;
  bf16* out = (z == 0) ? q : (z == 1) ? k : v;
  const float scale = (z == 0) ? 0.125f : 1.0f;  // fold SCALE into q
  gemm_body<false>(xb, W, bias, out, scale, blockIdx.y * 128, blockIdx.x * 128);
}

__global__ __launch_bounds__(256) void k_gemm_o(
    const bf16* __restrict__ ctx, const bf16* __restrict__ weffo,
    const float* __restrict__ bo, float* __restrict__ out) {
  gemm_body<true>(ctx, weffo, bo, out, 1.0f, blockIdx.y * 128, blockIdx.x * 128);
}

// ---------------- V transpose: vt[bh][dd][l] = v[b*L + l][h*64 + dd] ----------------
__global__ __launch_bounds__(256) void k_transpose_v(const bf16* __restrict__ v,
                                                     bf16* __restrict__ vt) {
  const int lt = blockIdx.x, bh = blockIdx.y;
  const int b = bh >> 4, h = bh & 15;
  __shared__ __align__(16) bf16 tile[64][72];
  const int t = threadIdx.x;
  const int r = t >> 2, c0 = (t & 3) * 16;
  const bf16* src = v + (size_t)(b * LSEQ + lt * 64) * DIM + h * HD;
  *(bf16x8*)(&tile[r][c0])     = *(const bf16x8*)(src + (size_t)r * DIM + c0);
  *(bf16x8*)(&tile[r][c0 + 8]) = *(const bf16x8*)(src + (size_t)r * DIM + c0 + 8);
  __syncthreads();
  bf16 ov[16];
#pragma unroll
  for (int j = 0; j < 16; ++j) ov[j] = tile[c0 + j][r];
  bf16* dst = vt + ((size_t)bh * HD + r) * LSEQ + lt * 64 + c0;
  *(bf16x8*)(dst)     = *(const bf16x8*)(ov);
  *(bf16x8*)(dst + 8) = *(const bf16x8*)(ov + 8);
}

// ---------------- flash attention ----------------
// grid: (16 q-blocks of 128 rows, 32 bh with b = y&1, h = y>>1). 4 waves x 32 q-rows.
// q pre-scaled by 0.125; K/V read direct from global (L2-resident, 256KB/head).
__global__ __launch_bounds__(256) void k_attn(
    const bf16* __restrict__ q, const bf16* __restrict__ k,
    const bf16* __restrict__ vt, const float* __restrict__ bias,
    bf16* __restrict__ ctx) {
  const int qb = blockIdx.x;
  const int b = blockIdx.y & 1, h = blockIdx.y >> 1;
  const int bh = b * NH + h;
  const int tid = threadIdx.x, w = tid >> 6, lane = tid & 63;
  const int l15 = lane & 15, l4 = lane >> 4;
  const int q0 = qb * 128 + w * 32;

  __shared__ __align__(16) bf16 p_lds[4][32][72];

  const bf16* qptr = q + (size_t)(b * LSEQ + q0) * DIM + h * HD;
  bf16x8 aQ[2][2];
#pragma unroll
  for (int m = 0; m < 2; ++m)
#pragma unroll
    for (int ks = 0; ks < 2; ++ks)
      aQ[m][ks] = *(const bf16x8*)(qptr + (size_t)(m * 16 + l15) * DIM + ks * 32 + l4 * 8);

  f32x4 acc[2][4] = {};
  float mrun[2][4], lrun[2][4];
#pragma unroll
  for (int m = 0; m < 2; ++m)
#pragma unroll
    for (int t = 0; t < 4; ++t) { mrun[m][t] = -1e30f; lrun[m][t] = 0.f; }

  const bf16* kbase = k + (size_t)(b * LSEQ) * DIM + h * HD;
  const bf16* vbase = vt + (size_t)bh * HD * LSEQ;
  const float* bbase = bias + ((size_t)h * LSEQ + q0) * LSEQ;

  for (int kt = 0; kt < LSEQ / 64; ++kt) {
    const int kk = kt * 64;
    // ---- S = QK^T (q pre-scaled) ----
    bf16x8 bK[4][2];
#pragma unroll
    for (int n = 0; n < 4; ++n)
#pragma unroll
      for (int ks = 0; ks < 2; ++ks)
        bK[n][ks] = *(const bf16x8*)(kbase + (size_t)(kk + n * 16 + l15) * DIM + ks * 32 + l4 * 8);
    f32x4 sc_[2][4];
#pragma unroll
    for (int m = 0; m < 2; ++m)
#pragma unroll
      for (int n = 0; n < 4; ++n) {
        f32x4 z = {0.f, 0.f, 0.f, 0.f};
        z = mfma16(aQ[m][0], bK[n][0], z);
        sc_[m][n] = mfma16(aQ[m][1], bK[n][1], z);
      }
    // ---- + bias ----
    const float* bp = bbase + kk;
#pragma unroll
    for (int m = 0; m < 2; ++m)
#pragma unroll
      for (int t = 0; t < 4; ++t) {
        const float* brow = bp + (size_t)(m * 16 + l4 * 4 + t) * LSEQ + l15;
#pragma unroll
        for (int n = 0; n < 4; ++n) sc_[m][n][t] += brow[n * 16];
      }
    // ---- online softmax ----
#pragma unroll
    for (int m = 0; m < 2; ++m) {
      float vm[4];
#pragma unroll
      for (int t = 0; t < 4; ++t)
        vm[t] = fmaxf(fmaxf(sc_[m][0][t], sc_[m][1][t]), fmaxf(sc_[m][2][t], sc_[m][3][t]));
#pragma unroll
      for (int off = 1; off <= 8; off <<= 1)
#pragma unroll
        for (int t = 0; t < 4; ++t) vm[t] = fmaxf(vm[t], __shfl_xor(vm[t], off));
      float scl[4], rs[4];
#pragma unroll
      for (int t = 0; t < 4; ++t) {
        const float mn = fmaxf(mrun[m][t], vm[t]);
        scl[t] = __expf(mrun[m][t] - mn);
        mrun[m][t] = mn;
        rs[t] = 0.f;
      }
#pragma unroll
      for (int n = 0; n < 4; ++n)
#pragma unroll
        for (int t = 0; t < 4; ++t) {
          const float p = __expf(sc_[m][n][t] - mrun[m][t]);
          sc_[m][n][t] = p;
          rs[t] += p;
        }
#pragma unroll
      for (int off = 1; off <= 8; off <<= 1)
#pragma unroll
        for (int t = 0; t < 4; ++t) rs[t] += __shfl_xor(rs[t], off);
#pragma unroll
      for (int t = 0; t < 4; ++t) lrun[m][t] = lrun[m][t] * scl[t] + rs[t];
#pragma unroll
      for (int d = 0; d < 4; ++d)
#pragma unroll
        for (int t = 0; t < 4; ++t) acc[m][d][t] *= scl[t];
#pragma unroll
      for (int n = 0; n < 4; ++n)
#pragma unroll
        for (int t = 0; t < 4; ++t)
          p_lds[w][m * 16 + l4 * 4 + t][n * 16 + l15] = (bf16)sc_[m][n][t];
    }
    // ---- PV ----
#pragma unroll
    for (int ks = 0; ks < 2; ++ks) {
      bf16x8 bV[4];
#pragma unroll
      for (int d = 0; d < 4; ++d)
        bV[d] = *(const bf16x8*)(vbase + (size_t)(d * 16 + l15) * LSEQ + kk + ks * 32 + l4 * 8);
#pragma unroll
      for (int m = 0; m < 2; ++m) {
        const bf16x8 aP = *(const bf16x8*)(&p_lds[w][m * 16 + l15][ks * 32 + l4 * 8]);
#pragma unroll
        for (int d = 0; d < 4; ++d) acc[m][d] = mfma16(aP, bV[d], acc[m][d]);
      }
    }
  }

  bf16* cptr = ctx + (size_t)(b * LSEQ + q0) * DIM + h * HD;
#pragma unroll
  for (int m = 0; m < 2; ++m)
#pragma unroll
    for (int d = 0; d < 4; ++d)
#pragma unroll
      for (int t = 0; t < 4; ++t)
        cptr[(size_t)(m * 16 + l4 * 4 + t) * DIM + d * 16 + l15] =
            (bf16)(acc[m][d][t] / lrun[m][t]);
}

// ---------------- launcher ----------------
extern "C" void kernel_launch(void* const* d_in, const int* in_sizes, int n_in,
                              void* d_out, int out_size, void* d_ws, size_t ws_size,
                              hipStream_t stream) {
  const float* x  = (const float*)d_in[0];
  const float* ab = (const float*)d_in[1];
  const float* Wq = (const float*)d_in[2];  const float* bq = (const float*)d_in[3];
  const float* Aq = (const float*)d_in[4];  const float* Bq = (const float*)d_in[5];
  const float* Wk = (const float*)d_in[6];  const float* bk = (const float*)d_in[7];
  const float* Ak = (const float*)d_in[8];  const float* Bk = (const float*)d_in[9];
  const float* Wv = (const float*)d_in[10]; const float* bv = (const float*)d_in[11];
  const float* Av = (const float*)d_in[12]; const float* Bv = (const float*)d_in[13];
  const float* Wo = (const float*)d_in[14]; const float* bo = (const float*)d_in[15];
  const float* Ao = (const float*)d_in[16]; const float* Bo = (const float*)d_in[17];

  uint8_t* ws = (uint8_t*)d_ws;
  const size_t SZ = (size_t)NTOK * DIM * sizeof(bf16);  // 8 MiB
  bf16* xb   = (bf16*)(ws + 0 * SZ);
  bf16* weff = (bf16*)(ws + 1 * SZ);   // [4][1024][1024] bf16 = 8 MiB
  bf16* qb   = (bf16*)(ws + 2 * SZ);
  bf16* kb   = (bf16*)(ws + 3 * SZ);
  bf16* vb   = (bf16*)(ws + 4 * SZ);
  bf16* vtb  = (bf16*)(ws + 5 * SZ);
  bf16* ctx  = (bf16*)(ws + 6 * SZ);

  k_cvt<<<dim3(NTOK * DIM / 1024), 256, 0, stream>>>(x, xb);

  WeffArgs wa;
  wa.W[0] = Wq; wa.A[0] = Aq; wa.B[0] = Bq; wa.out[0] = weff;
  wa.W[1] = Wk; wa.A[1] = Ak; wa.B[1] = Bk; wa.out[1] = weff + (size_t)DIM * DIM;
  wa.W[2] = Wv; wa.A[2] = Av; wa.B[2] = Bv; wa.out[2] = weff + 2 * (size_t)DIM * DIM;
  wa.W[3] = Wo; wa.A[3] = Ao; wa.B[3] = Bo; wa.out[3] = weff + 3 * (size_t)DIM * DIM;
  k_weff<<<dim3(DIM, 4), 256, 0, stream>>>(wa);

  k_gemm_qkv<<<dim3(8, 32, 3), 256, 0, stream>>>(xb, weff, bq, bk, bv, qb, kb, vb);
  k_transpose_v<<<dim3(32, 32), 256, 0, stream>>>(vb, vtb);
  k_attn<<<dim3(16, 32), 256, 0, stream>>>(qb, kb, vtb, ab, ctx);
  k_gemm_o<<<dim3(8, 32, 1), 256, 0, stream>>>(ctx, weff + 3 * (size_t)DIM * DIM, bo,
                                               (float*)d_out);
}

// Round 3
// 305.486 us; speedup vs baseline: 1.7324x; 1.7324x over previous
//
#include <hip/hip_runtime.h>
#include <cstdint>

typedef __bf16 bf16;
typedef __bf16 bf16x8 __attribute__((ext_vector_type(8)));
typedef __bf16 bf16x4 __attribute__((ext_vector_type(4)));
typedef float  f32x4  __attribute__((ext_vector_type(4)));
typedef float  f32x16 __attribute__((ext_vector_type(16)));
typedef int    i32x4  __attribute__((ext_vector_type(4)));

#define DIM   1024
#define LSEQ  2048
#define NH    16
#define HD    64
#define NTOK  4096

#define AS1C(p) ((const __attribute__((address_space(1))) void*)(unsigned long long)(uintptr_t)(p))
#define AS3P(p) ((__attribute__((address_space(3))) void*)(unsigned int)(uintptr_t)(p))

__device__ __forceinline__ f32x4 mfma16(bf16x8 a, bf16x8 b, f32x4 c) {
  return __builtin_amdgcn_mfma_f32_16x16x32_bf16(a, b, c, 0, 0, 0);
}
__device__ __forceinline__ f32x16 mfma32(bf16x8 a, bf16x8 b, f32x16 c) {
  return __builtin_amdgcn_mfma_f32_32x32x16_bf16(a, b, c, 0, 0, 0);
}
__device__ __forceinline__ int pk2(float a, float b) {
  unsigned short ua = __builtin_bit_cast(unsigned short, (bf16)a);
  unsigned short ub = __builtin_bit_cast(unsigned short, (bf16)b);
  return (int)ua | ((int)ub << 16);
}

// ---------------- x (fp32) -> bf16 ----------------
__global__ __launch_bounds__(256) void k_cvt(const float* __restrict__ x,
                                             bf16* __restrict__ xb) {
  const int i = (blockIdx.x * 256 + threadIdx.x) * 4;
  const f32x4 v = *(const f32x4*)(x + i);
  bf16x4 o;
  o[0] = (bf16)v[0]; o[1] = (bf16)v[1]; o[2] = (bf16)v[2]; o[3] = (bf16)v[3];
  *(bf16x4*)(xb + i) = o;
}

// ---------------- W_eff[o][d] = W[o][d] + 0.5 * sum_r A[d][r] * B[r][o] ----------------
struct WeffArgs {
  const float* W[4]; const float* A[4]; const float* B[4]; bf16* out[4];
};

__global__ __launch_bounds__(256) void k_weff(WeffArgs args) {
  const int o = blockIdx.x;
  const int z = blockIdx.y;
  const float* __restrict__ W  = args.W[z];
  const float* __restrict__ A  = args.A[z];
  const float* __restrict__ Bm = args.B[z];
  bf16* __restrict__ out = args.out[z];
  float Bo[16];
#pragma unroll
  for (int r = 0; r < 16; ++r) Bo[r] = Bm[r * DIM + o];
#pragma unroll
  for (int j = 0; j < 4; ++j) {
    const int d = j * 256 + (int)threadIdx.x;
    const float* Ar = A + (size_t)d * 16;
    float acc = 0.f;
#pragma unroll
    for (int r = 0; r < 16; ++r) acc += Ar[r] * Bo[r];
    out[(size_t)o * DIM + d] = (bf16)(W[(size_t)o * DIM + d] + 0.5f * acc);
  }
}

// ---------------- GEMM (m97 structure) ----------------
template <bool F32OUT>
__device__ __forceinline__ void gemm_body(const bf16* __restrict__ X,
                                          const bf16* __restrict__ W,
                                          const float* __restrict__ bias,
                                          void* __restrict__ out,
                                          float scale, int m0, int n0) {
  __shared__ __align__(16) bf16 As[128 * 32];
  __shared__ __align__(16) bf16 Bs[128 * 32];
  const int tid  = threadIdx.x;
  const int lane = tid & 63, w = tid >> 6;
  const int l15 = lane & 15, l4 = lane >> 4;
  const int wr = w >> 1, wc = w & 1;
  const int srow = w * 16 + (lane >> 2);
  const int scol = (lane & 3) * 8;

  f32x4 acc[4][4] = {};
  const bf16* ag = X + (size_t)m0 * DIM;
  const bf16* bg = W + (size_t)n0 * DIM;

  for (int kt = 0; kt < DIM / 32; ++kt) {
    const int k0 = kt * 32;
#pragma unroll
    for (int j = 0; j < 2; ++j) {
      const int row = j * 64 + srow;
      __builtin_amdgcn_global_load_lds(AS1C(ag + (size_t)row * DIM + k0 + scol),
                                       AS3P(As + (j * 64 + w * 16) * 32), 16, 0, 0);
      __builtin_amdgcn_global_load_lds(AS1C(bg + (size_t)row * DIM + k0 + scol),
                                       AS3P(Bs + (j * 64 + w * 16) * 32), 16, 0, 0);
    }
    __syncthreads();
    bf16x8 af[4], bfr[4];
#pragma unroll
    for (int m = 0; m < 4; ++m)
      af[m] = *(const bf16x8*)(As + (wr * 64 + m * 16 + l15) * 32 + l4 * 8);
#pragma unroll
    for (int n = 0; n < 4; ++n)
      bfr[n] = *(const bf16x8*)(Bs + (wc * 64 + n * 16 + l15) * 32 + l4 * 8);
#pragma unroll
    for (int m = 0; m < 4; ++m)
#pragma unroll
      for (int n = 0; n < 4; ++n)
        acc[m][n] = mfma16(af[m], bfr[n], acc[m][n]);
    __syncthreads();
  }

#pragma unroll
  for (int m = 0; m < 4; ++m) {
    const int r0 = m0 + wr * 64 + m * 16 + l4 * 4;
#pragma unroll
    for (int n = 0; n < 4; ++n) {
      const int c = n0 + wc * 64 + n * 16 + l15;
      const float bc = bias[c];
#pragma unroll
      for (int t = 0; t < 4; ++t) {
        const float y = (acc[m][n][t] + bc) * scale;
        if constexpr (F32OUT)
          ((float*)out)[(size_t)(r0 + t) * DIM + c] = y;
        else
          ((bf16*)out)[(size_t)(r0 + t) * DIM + c] = (bf16)y;
      }
    }
  }
}

__global__ __launch_bounds__(256) void k_gemm_qkv(
    const bf16* __restrict__ xb, const bf16* __restrict__ weff,
    const float* __restrict__ bq, const float* __restrict__ bk,
    const float* __restrict__ bv,
    bf16* __restrict__ q, bf16* __restrict__ k, bf16* __restrict__ v) {
  const int z = blockIdx.z;
  const bf16* W = weff + (size_t)z * DIM * DIM;
  const float* bias = (z == 0) ? bq : (z == 1) ? bk : bv;
  bf16* out = (z == 0) ? q : (z == 1) ? k : v;
  const float scale = (z == 0) ? 0.125f : 1.0f;
  gemm_body<false>(xb, W, bias, out, scale, blockIdx.y * 128, blockIdx.x * 128);
}

__global__ __launch_bounds__(256) void k_gemm_o(
    const bf16* __restrict__ ctx, const bf16* __restrict__ weffo,
    const float* __restrict__ bo, float* __restrict__ out) {
  gemm_body<true>(ctx, weffo, bo, out, 1.0f, blockIdx.y * 128, blockIdx.x * 128);
}

// ---------------- V transpose: vt[bh][dd][l] = v[b*L + l][h*64 + dd] ----------------
__global__ __launch_bounds__(256) void k_transpose_v(const bf16* __restrict__ v,
                                                     bf16* __restrict__ vt) {
  const int lt = blockIdx.x, bh = blockIdx.y;
  const int b = bh >> 4, h = bh & 15;
  __shared__ __align__(16) bf16 tile[64][72];
  const int t = threadIdx.x;
  const int r = t >> 2, c0 = (t & 3) * 16;
  const bf16* src = v + (size_t)(b * LSEQ + lt * 64) * DIM + h * HD;
  *(bf16x8*)(&tile[r][c0])     = *(const bf16x8*)(src + (size_t)r * DIM + c0);
  *(bf16x8*)(&tile[r][c0 + 8]) = *(const bf16x8*)(src + (size_t)r * DIM + c0 + 8);
  __syncthreads();
  bf16 ov[16];
#pragma unroll
  for (int j = 0; j < 16; ++j) ov[j] = tile[c0 + j][r];
  bf16* dst = vt + ((size_t)bh * HD + r) * LSEQ + lt * 64 + c0;
  *(bf16x8*)(dst)     = *(const bf16x8*)(ov);
  *(bf16x8*)(dst + 8) = *(const bf16x8*)(ov + 8);
}

// ---------------- flash attention, swapped-operand 32x32 structure ----------------
// grid (16, 32): x = 128-row q-tile (4 waves x 32 rows), y: b = y&1, h = y>>1.
// Per lane: one q-row (q = lane&31). S^T = mfma(K,Q); out^T = mfma(V^T,P^T).
// Cross-half exchange via __shfl_xor(.,32) (semantics-certain; permlane later).
__global__ __launch_bounds__(256) void k_attn(
    const bf16* __restrict__ q, const bf16* __restrict__ k,
    const bf16* __restrict__ vt, const float* __restrict__ bias,
    bf16* __restrict__ ctx) {
  const int tid = threadIdx.x, w = tid >> 6, lane = tid & 63;
  const int l31 = lane & 31, hi = lane >> 5;
  const int b = blockIdx.y & 1, h = blockIdx.y >> 1;
  const int q0 = blockIdx.x * 128 + w * 32;

  // Q fragment: B-operand of S^T = K*Q  (lane holds Q[q0+l31][16c+8hi+j])
  const bf16* qrow = q + (size_t)(b * LSEQ + q0 + l31) * DIM + h * HD;
  bf16x8 Qf[4];
#pragma unroll
  for (int c = 0; c < 4; ++c) Qf[c] = *(const bf16x8*)(qrow + c * 16 + hi * 8);

  const bf16* kb = k + ((size_t)(b * LSEQ + l31)) * DIM + h * HD + hi * 8;
  const bf16* vb = vt + ((size_t)(b * NH + h) * HD + l31) * LSEQ + hi * 8;
  const float* bb = bias + ((size_t)(h * LSEQ) + q0 + l31) * LSEQ + hi * 4;

  f32x16 acc0 = {}, acc1 = {};
  float mrun = -3e38f, lrun = 0.f;

  bf16x8 KA[4], KB[4];
  f32x4 bA[4], bB[4];

#define LOADK(dst, t)                                                       \
  { const bf16* kp_ = kb + (size_t)(t) * 32 * DIM;                          \
    _Pragma("unroll") for (int c_ = 0; c_ < 4; ++c_)                        \
      dst[c_] = *(const bf16x8*)(kp_ + c_ * 16); }
#define LOADBIAS(dst, t)                                                    \
  { const float* bp_ = bb + (t) * 32;                                       \
    _Pragma("unroll") for (int g_ = 0; g_ < 4; ++g_)                        \
      dst[g_] = *(const f32x4*)(bp_ + g_ * 8); }
#define LOADV(dst, t)                                                       \
  { _Pragma("unroll") for (int n_ = 0; n_ < 2; ++n_)                        \
    _Pragma("unroll") for (int c_ = 0; c_ < 2; ++c_)                        \
      dst[n_][c_] = *(const bf16x8*)(vb + (size_t)n_ * 32 * LSEQ + (t) * 32 + c_ * 16); }

  auto step = [&](const bf16x8* Kf, const f32x4* Bf, bf16x8 Vf[2][2]) {
    f32x16 s = {};
#pragma unroll
    for (int c = 0; c < 4; ++c) s = mfma32(Kf[c], Qf[c], s);
    // p[r] = S^T value at k_local = (r&3) + 8*(r>>2) + 4*hi, plus bias
    float p[16];
#pragma unroll
    for (int r = 0; r < 16; ++r) p[r] = s[r] + Bf[r >> 2][r & 3];
    // row max: in-register tree + one cross-half exchange
    float m8[8];
#pragma unroll
    for (int i = 0; i < 8; ++i) m8[i] = fmaxf(p[i], p[i + 8]);
    float tm = fmaxf(fmaxf(fmaxf(m8[0], m8[4]), fmaxf(m8[1], m8[5])),
                     fmaxf(fmaxf(m8[2], m8[6]), fmaxf(m8[3], m8[7])));
    tm = fmaxf(tm, __shfl_xor(tm, 32));
    if (!__all(tm <= mrun + 8.0f)) {   // defer-max (T13)
      const float mn = fmaxf(mrun, tm);
      const float scl = __expf(mrun - mn);
      mrun = mn;
      lrun *= scl;
#pragma unroll
      for (int r = 0; r < 16; ++r) { acc0[r] *= scl; acc1[r] *= scl; }
    }
#pragma unroll
    for (int r = 0; r < 16; ++r) p[r] = __expf(p[r] - mrun);
    float s8[8];
#pragma unroll
    for (int i = 0; i < 8; ++i) s8[i] = p[i] + p[i + 8];
    float rs = ((s8[0] + s8[1]) + (s8[2] + s8[3])) + ((s8[4] + s8[5]) + (s8[6] + s8[7]));
    rs += __shfl_xor(rs, 32);
    lrun += rs;
    // P^T B-fragments: slots j on (l31,hi) need k_local = c*16 + hi*8 + j.
    // own A = pk2(p[c8+0..3]) covers k_local base+(0..3)+4hi; own B = p[c8+4..7]
    // covers base+8+(0..3)+4hi. Cross-half values fetched via shfl_xor 32.
#pragma unroll
    for (int c = 0; c < 2; ++c) {
      const int c8 = c * 8;
      const int A0 = pk2(p[c8 + 0], p[c8 + 1]);
      const int A1 = pk2(p[c8 + 2], p[c8 + 3]);
      const int B0 = pk2(p[c8 + 4], p[c8 + 5]);
      const int B1 = pk2(p[c8 + 6], p[c8 + 7]);
      const int pA0 = __shfl_xor(A0, 32), pA1 = __shfl_xor(A1, 32);
      const int pB0 = __shfl_xor(B0, 32), pB1 = __shfl_xor(B1, 32);
      i32x4 fi;
      fi[0] = hi ? pB0 : A0;   // j=0,1
      fi[1] = hi ? pB1 : A1;   // j=2,3
      fi[2] = hi ? B0 : pA0;   // j=4,5
      fi[3] = hi ? B1 : pA1;   // j=6,7
      const bf16x8 pf = __builtin_bit_cast(bf16x8, fi);
      acc0 = mfma32(Vf[0][c], pf, acc0);
      acc1 = mfma32(Vf[1][c], pf, acc1);
    }
  };

  LOADK(KA, 0); LOADBIAS(bA, 0);
  for (int t = 0; t < 64; t += 2) {
    bf16x8 V0[2][2], V1[2][2];
    LOADV(V0, t);
    LOADK(KB, t + 1); LOADBIAS(bB, t + 1);
    step(KA, bA, V0);
    LOADV(V1, t + 1);
    LOADK(KA, (t + 2) & 63); LOADBIAS(bA, (t + 2) & 63);
    step(KB, bB, V1);
  }
#undef LOADK
#undef LOADBIAS
#undef LOADV

  const float inv = 1.0f / lrun;
  bf16* cp = ctx + (size_t)(b * LSEQ + q0 + l31) * DIM + h * HD;
#pragma unroll
  for (int r = 0; r < 16; ++r) {
    const int dr = (r & 3) + 8 * (r >> 2) + 4 * hi;
    cp[dr]      = (bf16)(acc0[r] * inv);
    cp[32 + dr] = (bf16)(acc1[r] * inv);
  }
}

// ---------------- launcher ----------------
extern "C" void kernel_launch(void* const* d_in, const int* in_sizes, int n_in,
                              void* d_out, int out_size, void* d_ws, size_t ws_size,
                              hipStream_t stream) {
  const float* x  = (const float*)d_in[0];
  const float* ab = (const float*)d_in[1];
  const float* Wq = (const float*)d_in[2];  const float* bq = (const float*)d_in[3];
  const float* Aq = (const float*)d_in[4];  const float* Bq = (const float*)d_in[5];
  const float* Wk = (const float*)d_in[6];  const float* bk = (const float*)d_in[7];
  const float* Ak = (const float*)d_in[8];  const float* Bk = (const float*)d_in[9];
  const float* Wv = (const float*)d_in[10]; const float* bv = (const float*)d_in[11];
  const float* Av = (const float*)d_in[12]; const float* Bv = (const float*)d_in[13];
  const float* Wo = (const float*)d_in[14]; const float* bo = (const float*)d_in[15];
  const float* Ao = (const float*)d_in[16]; const float* Bo = (const float*)d_in[17];

  uint8_t* ws = (uint8_t*)d_ws;
  const size_t SZ = (size_t)NTOK * DIM * sizeof(bf16);  // 8 MiB
  bf16* xb   = (bf16*)(ws + 0 * SZ);
  bf16* weff = (bf16*)(ws + 1 * SZ);
  bf16* qb   = (bf16*)(ws + 2 * SZ);
  bf16* kb   = (bf16*)(ws + 3 * SZ);
  bf16* vb   = (bf16*)(ws + 4 * SZ);
  bf16* vtb  = (bf16*)(ws + 5 * SZ);
  bf16* ctx  = (bf16*)(ws + 6 * SZ);

  k_cvt<<<dim3(NTOK * DIM / 1024), 256, 0, stream>>>(x, xb);

  WeffArgs wa;
  wa.W[0] = Wq; wa.A[0] = Aq; wa.B[0] = Bq; wa.out[0] = weff;
  wa.W[1] = Wk; wa.A[1] = Ak; wa.B[1] = Bk; wa.out[1] = weff + (size_t)DIM * DIM;
  wa.W[2] = Wv; wa.A[2] = Av; wa.B[2] = Bv; wa.out[2] = weff + 2 * (size_t)DIM * DIM;
  wa.W[3] = Wo; wa.A[3] = Ao; wa.B[3] = Bo; wa.out[3] = weff + 3 * (size_t)DIM * DIM;
  k_weff<<<dim3(DIM, 4), 256, 0, stream>>>(wa);

  k_gemm_qkv<<<dim3(8, 32, 3), 256, 0, stream>>>(xb, weff, bq, bk, bv, qb, kb, vb);
  k_transpose_v<<<dim3(32, 32), 256, 0, stream>>>(vb, vtb);
  k_attn<<<dim3(16, 32), 256, 0, stream>>>(qb, kb, vtb, ab, ctx);
  k_gemm_o<<<dim3(8, 32, 1), 256, 0, stream>>>(ctx, weff + 3 * (size_t)DIM * DIM, bo,
                                               (float*)d_out);
}

// Round 4
// 209.454 us; speedup vs baseline: 2.5266x; 1.4585x over previous
//
#include <hip/hip_runtime.h>
#include <cstdint>

typedef __bf16 bf16;
typedef __bf16 bf16x8 __attribute__((ext_vector_type(8)));
typedef __bf16 bf16x4 __attribute__((ext_vector_type(4)));
typedef float  f32x4  __attribute__((ext_vector_type(4)));
typedef float  f32x16 __attribute__((ext_vector_type(16)));
typedef int    i32x4  __attribute__((ext_vector_type(4)));

#define DIM   1024
#define LSEQ  2048
#define NH    16
#define HD    64
#define NTOK  4096

#define AS1C(p) ((const __attribute__((address_space(1))) void*)(unsigned long long)(uintptr_t)(p))
#define AS3P(p) ((__attribute__((address_space(3))) void*)(unsigned int)(uintptr_t)(p))
#define SB0 __builtin_amdgcn_sched_barrier(0)

__device__ __forceinline__ f32x4 mfma16(bf16x8 a, bf16x8 b, f32x4 c) {
  return __builtin_amdgcn_mfma_f32_16x16x32_bf16(a, b, c, 0, 0, 0);
}
__device__ __forceinline__ f32x16 mfma32(bf16x8 a, bf16x8 b, f32x16 c) {
  return __builtin_amdgcn_mfma_f32_32x32x16_bf16(a, b, c, 0, 0, 0);
}
__device__ __forceinline__ int pk2(float a, float b) {
  unsigned short ua = __builtin_bit_cast(unsigned short, (bf16)a);
  unsigned short ub = __builtin_bit_cast(unsigned short, (bf16)b);
  return (int)ua | ((int)ub << 16);
}

// ---------------- x (fp32) -> bf16 ----------------
__global__ __launch_bounds__(256) void k_cvt(const float* __restrict__ x,
                                             bf16* __restrict__ xb) {
  const int i = (blockIdx.x * 256 + threadIdx.x) * 4;
  const f32x4 v = *(const f32x4*)(x + i);
  bf16x4 o;
  o[0] = (bf16)v[0]; o[1] = (bf16)v[1]; o[2] = (bf16)v[2]; o[3] = (bf16)v[3];
  *(bf16x4*)(xb + i) = o;
}

// ---------------- W_eff[o][d] = W[o][d] + 0.5 * sum_r A[d][r] * B[r][o] ----------------
struct WeffArgs {
  const float* W[4]; const float* A[4]; const float* B[4]; bf16* out[4];
};

__global__ __launch_bounds__(256) void k_weff(WeffArgs args) {
  const int o = blockIdx.x;
  const int z = blockIdx.y;
  const float* __restrict__ W  = args.W[z];
  const float* __restrict__ A  = args.A[z];
  const float* __restrict__ Bm = args.B[z];
  bf16* __restrict__ out = args.out[z];
  float Bo[16];
#pragma unroll
  for (int r = 0; r < 16; ++r) Bo[r] = Bm[r * DIM + o];
#pragma unroll
  for (int j = 0; j < 4; ++j) {
    const int d = j * 256 + (int)threadIdx.x;
    const float* Ar = A + (size_t)d * 16;
    float acc = 0.f;
#pragma unroll
    for (int r = 0; r < 16; ++r) acc += Ar[r] * Bo[r];
    out[(size_t)o * DIM + d] = (bf16)(W[(size_t)o * DIM + d] + 0.5f * acc);
  }
}

// ---------------- GEMM (m97 structure) ----------------
template <bool F32OUT>
__device__ __forceinline__ void gemm_body(const bf16* __restrict__ X,
                                          const bf16* __restrict__ W,
                                          const float* __restrict__ bias,
                                          void* __restrict__ out,
                                          float scale, int m0, int n0) {
  __shared__ __align__(16) bf16 As[128 * 32];
  __shared__ __align__(16) bf16 Bs[128 * 32];
  const int tid  = threadIdx.x;
  const int lane = tid & 63, w = tid >> 6;
  const int l15 = lane & 15, l4 = lane >> 4;
  const int wr = w >> 1, wc = w & 1;
  const int srow = w * 16 + (lane >> 2);
  const int scol = (lane & 3) * 8;

  f32x4 acc[4][4] = {};
  const bf16* ag = X + (size_t)m0 * DIM;
  const bf16* bg = W + (size_t)n0 * DIM;

  for (int kt = 0; kt < DIM / 32; ++kt) {
    const int k0 = kt * 32;
#pragma unroll
    for (int j = 0; j < 2; ++j) {
      const int row = j * 64 + srow;
      __builtin_amdgcn_global_load_lds(AS1C(ag + (size_t)row * DIM + k0 + scol),
                                       AS3P(As + (j * 64 + w * 16) * 32), 16, 0, 0);
      __builtin_amdgcn_global_load_lds(AS1C(bg + (size_t)row * DIM + k0 + scol),
                                       AS3P(Bs + (j * 64 + w * 16) * 32), 16, 0, 0);
    }
    __syncthreads();
    bf16x8 af[4], bfr[4];
#pragma unroll
    for (int m = 0; m < 4; ++m)
      af[m] = *(const bf16x8*)(As + (wr * 64 + m * 16 + l15) * 32 + l4 * 8);
#pragma unroll
    for (int n = 0; n < 4; ++n)
      bfr[n] = *(const bf16x8*)(Bs + (wc * 64 + n * 16 + l15) * 32 + l4 * 8);
#pragma unroll
    for (int m = 0; m < 4; ++m)
#pragma unroll
      for (int n = 0; n < 4; ++n)
        acc[m][n] = mfma16(af[m], bfr[n], acc[m][n]);
    __syncthreads();
  }

#pragma unroll
  for (int m = 0; m < 4; ++m) {
    const int r0 = m0 + wr * 64 + m * 16 + l4 * 4;
#pragma unroll
    for (int n = 0; n < 4; ++n) {
      const int c = n0 + wc * 64 + n * 16 + l15;
      const float bc = bias[c];
#pragma unroll
      for (int t = 0; t < 4; ++t) {
        const float y = (acc[m][n][t] + bc) * scale;
        if constexpr (F32OUT)
          ((float*)out)[(size_t)(r0 + t) * DIM + c] = y;
        else
          ((bf16*)out)[(size_t)(r0 + t) * DIM + c] = (bf16)y;
      }
    }
  }
}

__global__ __launch_bounds__(256) void k_gemm_qkv(
    const bf16* __restrict__ xb, const bf16* __restrict__ weff,
    const float* __restrict__ bq, const float* __restrict__ bk,
    const float* __restrict__ bv,
    bf16* __restrict__ q, bf16* __restrict__ k, bf16* __restrict__ v) {
  const int z = blockIdx.z;
  const bf16* W = weff + (size_t)z * DIM * DIM;
  const float* bias = (z == 0) ? bq : (z == 1) ? bk : bv;
  bf16* out = (z == 0) ? q : (z == 1) ? k : v;
  const float scale = (z == 0) ? 0.125f : 1.0f;
  gemm_body<false>(xb, W, bias, out, scale, blockIdx.y * 128, blockIdx.x * 128);
}

__global__ __launch_bounds__(256) void k_gemm_o(
    const bf16* __restrict__ ctx, const bf16* __restrict__ weffo,
    const float* __restrict__ bo, float* __restrict__ out) {
  gemm_body<true>(ctx, weffo, bo, out, 1.0f, blockIdx.y * 128, blockIdx.x * 128);
}

// ---------------- K/V fragment pre-pass ----------------
// vf[bh][t][n*2+c][lane] (bf16x8): V^T[n*32+l31][t*32 + c*16 + hi*8 + j]
// kf[bh][t][c][lane]     (bf16x8): K[t*32 + l31][h*64 + c*16 + hi*8 + j]
// Makes every K/V load in k_attn a fully-coalesced 1KB wave instruction.
__global__ __launch_bounds__(256) void k_vfrag(const bf16* __restrict__ v,
                                               const bf16* __restrict__ k,
                                               bf16* __restrict__ vf,
                                               bf16* __restrict__ kf) {
  const int lt = blockIdx.x, bh = blockIdx.y;
  const int b = bh >> 4, h = bh & 15;
  __shared__ __align__(16) bf16 tile[64][72];
  const int tid = threadIdx.x;
  const int r = tid >> 2, c0 = (tid & 3) * 16;
  const bf16* src = v + (size_t)(b * LSEQ + lt * 64) * DIM + h * HD;
  *(bf16x8*)(&tile[r][c0])     = *(const bf16x8*)(src + (size_t)r * DIM + c0);
  *(bf16x8*)(&tile[r][c0 + 8]) = *(const bf16x8*)(src + (size_t)r * DIM + c0 + 8);
  __syncthreads();
  const int w = tid >> 6, lane = tid & 63, l31 = lane & 31, hi = lane >> 5;
  // V fragments: wave w -> tt = w>>1, n = w&1; c in {0,1}
  {
    const int tt = w >> 1, n = w & 1;
    const int t = lt * 2 + tt;
#pragma unroll
    for (int c = 0; c < 2; ++c) {
      bf16 tmp[8];
#pragma unroll
      for (int j = 0; j < 8; ++j)
        tmp[j] = tile[tt * 32 + c * 16 + hi * 8 + j][n * 32 + l31];
      *(bf16x8*)(vf + ((((size_t)bh * 64 + t) * 4 + n * 2 + c) * 64 + lane) * 8) =
          *(bf16x8*)tmp;
    }
  }
  // K fragments: wave w -> t = lt*2 + (w&1), c in {w>>1, 2+(w>>1)}
  {
    const int t = lt * 2 + (w & 1);
    const bf16* krow = k + (size_t)(b * LSEQ + t * 32 + l31) * DIM + h * HD + hi * 8;
#pragma unroll
    for (int cc = 0; cc < 2; ++cc) {
      const int c = (w >> 1) + cc * 2;
      *(bf16x8*)(kf + ((((size_t)bh * 64 + t) * 4 + c) * 64 + lane) * 8) =
          *(const bf16x8*)(krow + c * 16);
    }
  }
}

// ---------------- flash attention, swapped-operand 32x32 structure ----------------
// All hot-loop loads coalesced: K/V from fragment arrays (L2), bias via
// global_load_lds into triple-buffered per-wave LDS (2-step prefetch, counted
// vmcnt), XOR-swizzle folded into the glds SOURCE address (T21).
__global__ __launch_bounds__(256, 2) void k_attn(
    const bf16* __restrict__ q, const bf16* __restrict__ kf,
    const bf16* __restrict__ vf, const float* __restrict__ bias,
    bf16* __restrict__ ctx) {
  const int tid = threadIdx.x, w = tid >> 6, lane = tid & 63;
  const int l31 = lane & 31, hi = lane >> 5;
  const int b = blockIdx.y & 1, h = blockIdx.y >> 1;
  const int bh = b * NH + h;
  const int q0 = blockIdx.x * 128 + w * 32;

  __shared__ __align__(16) float blds[4][3][1024];

  // Q fragment: B-operand of S^T = K*Q
  const bf16* qrow = q + (size_t)(b * LSEQ + q0 + l31) * DIM + h * HD;
  bf16x8 Qf[4];
#pragma unroll
  for (int c = 0; c < 4; ++c) Qf[c] = *(const bf16x8*)(qrow + c * 16 + hi * 8);

  const bf16x8* kfp = (const bf16x8*)kf + (size_t)bh * 256 * 64 + lane;
  const bf16x8* vfp = (const bf16x8*)vf + (size_t)bh * 256 * 64 + lane;

  // bias glds source (per lane): row q0 + g*8 + (lane>>3), float col swizzled
  const int lr = lane >> 3, lc = lane & 7;
  const float* bsrc = bias + ((size_t)h * LSEQ + q0 + lr) * LSEQ + 4 * (lc ^ lr);

  // LDS read offsets: lane (l31,hi), group gr reads bias[q0+l31][t*32+8gr+4hi+0..3]
  const unsigned bofs = (unsigned)(uintptr_t)AS3P(&blds[w][0][0]);
  const int sw = (l31 & 7) << 2;
  unsigned dro0 = 4u * (unsigned)(l31 * 32 + (((0 << 3) | (hi << 2)) ^ sw));
  unsigned dro1 = 4u * (unsigned)(l31 * 32 + (((1 << 3) | (hi << 2)) ^ sw));
  unsigned dro2 = 4u * (unsigned)(l31 * 32 + (((2 << 3) | (hi << 2)) ^ sw));
  unsigned dro3 = 4u * (unsigned)(l31 * 32 + (((3 << 3) | (hi << 2)) ^ sw));

  f32x16 acc0 = {}, acc1 = {};
  float mrun = -3e38f, lrun = 0.f;
  bf16x8 KA[4], KB[4], VA[2][2], VB[2][2];

#define GLDSB(t_, s_)                                                        \
  { const float* bp_ = bsrc + (size_t)(t_) * 32;                             \
    _Pragma("unroll") for (int g_ = 0; g_ < 4; ++g_)                         \
      __builtin_amdgcn_global_load_lds(AS1C(bp_ + (size_t)g_ * 8 * LSEQ),    \
                                       AS3P(&blds[w][s_][g_ * 256]), 16, 0, 0); }
#define LOADK(dst, t_)                                                      \
  _Pragma("unroll") for (int c_ = 0; c_ < 4; ++c_)                          \
    dst[c_] = kfp[((t_) * 4 + c_) * 64];
#define LOADV(dst, t_)                                                      \
  _Pragma("unroll") for (int u_ = 0; u_ < 4; ++u_)                          \
    dst[u_ >> 1][u_ & 1] = vfp[((t_) * 4 + u_) * 64];

  auto step = [&](const bf16x8 (&Kf)[4], const bf16x8 (&Vf)[2][2], int slot) {
    const unsigned so = bofs + (unsigned)slot * 4096u;
    f32x4 r0, r1, r2, r3;
    asm volatile(
        "ds_read_b128 %0, %4\n\t"
        "ds_read_b128 %1, %5\n\t"
        "ds_read_b128 %2, %6\n\t"
        "ds_read_b128 %3, %7"
        : "=&v"(r0), "=&v"(r1), "=&v"(r2), "=&v"(r3)
        : "v"(so + dro0), "v"(so + dro1), "v"(so + dro2), "v"(so + dro3));
    f32x16 s = {};
#pragma unroll
    for (int c = 0; c < 4; ++c) s = mfma32(Kf[c], Qf[c], s);
    asm volatile("s_waitcnt lgkmcnt(0)"
                 : "+v"(r0), "+v"(r1), "+v"(r2), "+v"(r3));
    SB0;
    f32x4 br[4] = {r0, r1, r2, r3};
    // p[r] = S^T at k_local = (r&3) + 8*(r>>2) + 4*hi, plus bias
    float p[16];
#pragma unroll
    for (int r = 0; r < 16; ++r) p[r] = s[r] + br[r >> 2][r & 3];
    float m8[8];
#pragma unroll
    for (int i = 0; i < 8; ++i) m8[i] = fmaxf(p[i], p[i + 8]);
    float tm = fmaxf(fmaxf(fmaxf(m8[0], m8[4]), fmaxf(m8[1], m8[5])),
                     fmaxf(fmaxf(m8[2], m8[6]), fmaxf(m8[3], m8[7])));
    tm = fmaxf(tm, __shfl_xor(tm, 32));
    if (!__all(tm <= mrun + 8.0f)) {   // defer-max (T13)
      const float mn = fmaxf(mrun, tm);
      const float scl = __expf(mrun - mn);
      mrun = mn;
      lrun *= scl;
#pragma unroll
      for (int r = 0; r < 16; ++r) { acc0[r] *= scl; acc1[r] *= scl; }
    }
#pragma unroll
    for (int r = 0; r < 16; ++r) p[r] = __expf(p[r] - mrun);
    float s8[8];
#pragma unroll
    for (int i = 0; i < 8; ++i) s8[i] = p[i] + p[i + 8];
    float rs = ((s8[0] + s8[1]) + (s8[2] + s8[3])) + ((s8[4] + s8[5]) + (s8[6] + s8[7]));
    rs += __shfl_xor(rs, 32);
    lrun += rs;
    // P^T B-fragments via pack + cross-half shuffle
#pragma unroll
    for (int c = 0; c < 2; ++c) {
      const int c8 = c * 8;
      const int A0 = pk2(p[c8 + 0], p[c8 + 1]);
      const int A1 = pk2(p[c8 + 2], p[c8 + 3]);
      const int B0 = pk2(p[c8 + 4], p[c8 + 5]);
      const int B1 = pk2(p[c8 + 6], p[c8 + 7]);
      const int pA0 = __shfl_xor(A0, 32), pA1 = __shfl_xor(A1, 32);
      const int pB0 = __shfl_xor(B0, 32), pB1 = __shfl_xor(B1, 32);
      i32x4 fi;
      fi[0] = hi ? pB0 : A0;
      fi[1] = hi ? pB1 : A1;
      fi[2] = hi ? B0 : pA0;
      fi[3] = hi ? B1 : pA1;
      const bf16x8 pf = __builtin_bit_cast(bf16x8, fi);
      acc0 = mfma32(Vf[0][c], pf, acc0);
      acc1 = mfma32(Vf[1][c], pf, acc1);
    }
  };

  // prologue: bias for steps 0,1 in flight; K/V(0) in flight
  GLDSB(0, 0); SB0;
  GLDSB(1, 1); SB0;
  LOADK(KA, 0); LOADV(VA, 0); SB0;

  for (int t = 0; t < 64; t += 2) {
    // ---- even step t ----
    { const int tc = (t + 2 > 63) ? 63 : t + 2; GLDSB(tc, (t + 2) % 3); } SB0;
    LOADK(KB, t + 1); LOADV(VB, t + 1); SB0;
    asm volatile("s_waitcnt vmcnt(24)" ::: "memory");
    step(KA, VA, t % 3);
    // ---- odd step t+1 ----
    { const int tc = (t + 3 > 63) ? 63 : t + 3; GLDSB(tc, (t + 3) % 3); } SB0;
    { const int tn = (t + 2 > 63) ? 63 : t + 2; LOADK(KA, tn); LOADV(VA, tn); } SB0;
    asm volatile("s_waitcnt vmcnt(24)" ::: "memory");
    step(KB, VB, (t + 1) % 3);
  }
#undef GLDSB
#undef LOADK
#undef LOADV

  const float inv = 1.0f / lrun;
  bf16* cp = ctx + (size_t)(b * LSEQ + q0 + l31) * DIM + h * HD;
#pragma unroll
  for (int r = 0; r < 16; ++r) {
    const int dr = (r & 3) + 8 * (r >> 2) + 4 * hi;
    cp[dr]      = (bf16)(acc0[r] * inv);
    cp[32 + dr] = (bf16)(acc1[r] * inv);
  }
}

// ---------------- launcher ----------------
extern "C" void kernel_launch(void* const* d_in, const int* in_sizes, int n_in,
                              void* d_out, int out_size, void* d_ws, size_t ws_size,
                              hipStream_t stream) {
  const float* x  = (const float*)d_in[0];
  const float* ab = (const float*)d_in[1];
  const float* Wq = (const float*)d_in[2];  const float* bq = (const float*)d_in[3];
  const float* Aq = (const float*)d_in[4];  const float* Bq = (const float*)d_in[5];
  const float* Wk = (const float*)d_in[6];  const float* bk = (const float*)d_in[7];
  const float* Ak = (const float*)d_in[8];  const float* Bk = (const float*)d_in[9];
  const float* Wv = (const float*)d_in[10]; const float* bv = (const float*)d_in[11];
  const float* Av = (const float*)d_in[12]; const float* Bv = (const float*)d_in[13];
  const float* Wo = (const float*)d_in[14]; const float* bo = (const float*)d_in[15];
  const float* Ao = (const float*)d_in[16]; const float* Bo = (const float*)d_in[17];

  uint8_t* ws = (uint8_t*)d_ws;
  const size_t SZ = (size_t)NTOK * DIM * sizeof(bf16);  // 8 MiB
  bf16* xb   = (bf16*)(ws + 0 * SZ);
  bf16* weff = (bf16*)(ws + 1 * SZ);
  bf16* qb   = (bf16*)(ws + 2 * SZ);
  bf16* kb   = (bf16*)(ws + 3 * SZ);
  bf16* vb   = (bf16*)(ws + 4 * SZ);
  bf16* kfb  = (bf16*)(ws + 5 * SZ);
  bf16* vfb  = (bf16*)(ws + 6 * SZ);
  bf16* ctx  = (bf16*)(ws + 7 * SZ);

  k_cvt<<<dim3(NTOK * DIM / 1024), 256, 0, stream>>>(x, xb);

  WeffArgs wa;
  wa.W[0] = Wq; wa.A[0] = Aq; wa.B[0] = Bq; wa.out[0] = weff;
  wa.W[1] = Wk; wa.A[1] = Ak; wa.B[1] = Bk; wa.out[1] = weff + (size_t)DIM * DIM;
  wa.W[2] = Wv; wa.A[2] = Av; wa.B[2] = Bv; wa.out[2] = weff + 2 * (size_t)DIM * DIM;
  wa.W[3] = Wo; wa.A[3] = Ao; wa.B[3] = Bo; wa.out[3] = weff + 3 * (size_t)DIM * DIM;
  k_weff<<<dim3(DIM, 4), 256, 0, stream>>>(wa);

  k_gemm_qkv<<<dim3(8, 32, 3), 256, 0, stream>>>(xb, weff, bq, bk, bv, qb, kb, vb);
  k_vfrag<<<dim3(32, 32), 256, 0, stream>>>(vb, kb, vfb, kfb);
  k_attn<<<dim3(16, 32), 256, 0, stream>>>(qb, kfb, vfb, ab, ctx);
  k_gemm_o<<<dim3(8, 32, 1), 256, 0, stream>>>(ctx, weff + 3 * (size_t)DIM * DIM, bo,
                                               (float*)d_out);
}

// Round 5
// 206.765 us; speedup vs baseline: 2.5595x; 1.0130x over previous
//
#include <hip/hip_runtime.h>
#include <cstdint>

typedef __bf16 bf16;
typedef __bf16 bf16x8 __attribute__((ext_vector_type(8)));
typedef __bf16 bf16x4 __attribute__((ext_vector_type(4)));
typedef float  f32x4  __attribute__((ext_vector_type(4)));
typedef float  f32x16 __attribute__((ext_vector_type(16)));
typedef int    i32x4  __attribute__((ext_vector_type(4)));

#define DIM   1024
#define LSEQ  2048
#define NH    16
#define HD    64
#define NTOK  4096

#define AS1C(p) ((const __attribute__((address_space(1))) void*)(unsigned long long)(uintptr_t)(p))
#define AS3P(p) ((__attribute__((address_space(3))) void*)(unsigned int)(uintptr_t)(p))
#define SB0 __builtin_amdgcn_sched_barrier(0)

__device__ __forceinline__ f32x4 mfma16(bf16x8 a, bf16x8 b, f32x4 c) {
  return __builtin_amdgcn_mfma_f32_16x16x32_bf16(a, b, c, 0, 0, 0);
}
__device__ __forceinline__ f32x16 mfma32(bf16x8 a, bf16x8 b, f32x16 c) {
  return __builtin_amdgcn_mfma_f32_32x32x16_bf16(a, b, c, 0, 0, 0);
}
__device__ __forceinline__ int pk2(float a, float b) {
  unsigned short ua = __builtin_bit_cast(unsigned short, (bf16)a);
  unsigned short ub = __builtin_bit_cast(unsigned short, (bf16)b);
  return (int)ua | ((int)ub << 16);
}

// ---------------- x (fp32) -> bf16 ----------------
__global__ __launch_bounds__(256) void k_cvt(const float* __restrict__ x,
                                             bf16* __restrict__ xb) {
  const int i = (blockIdx.x * 256 + threadIdx.x) * 4;
  const f32x4 v = *(const f32x4*)(x + i);
  bf16x4 o;
  o[0] = (bf16)v[0]; o[1] = (bf16)v[1]; o[2] = (bf16)v[2]; o[3] = (bf16)v[3];
  *(bf16x4*)(xb + i) = o;
}

// ---------------- W_eff[o][d] = W[o][d] + 0.5 * sum_r A[d][r] * B[r][o] ----------------
struct WeffArgs {
  const float* W[4]; const float* A[4]; const float* B[4]; bf16* out[4];
};

__global__ __launch_bounds__(256) void k_weff(WeffArgs args) {
  const int o = blockIdx.x;
  const int z = blockIdx.y;
  const float* __restrict__ W  = args.W[z];
  const float* __restrict__ A  = args.A[z];
  const float* __restrict__ Bm = args.B[z];
  bf16* __restrict__ out = args.out[z];
  float Bo[16];
#pragma unroll
  for (int r = 0; r < 16; ++r) Bo[r] = Bm[r * DIM + o];
#pragma unroll
  for (int j = 0; j < 4; ++j) {
    const int d = j * 256 + (int)threadIdx.x;
    const float* Ar = A + (size_t)d * 16;
    float acc = 0.f;
#pragma unroll
    for (int r = 0; r < 16; ++r) acc += Ar[r] * Bo[r];
    out[(size_t)o * DIM + d] = (bf16)(W[(size_t)o * DIM + d] + 0.5f * acc);
  }
}

// ---------------- GEMM (m97 structure), BN = NF*32 ----------------
template <int NF, bool F32OUT>
__device__ __forceinline__ void gemm_body(const bf16* __restrict__ X,
                                          const bf16* __restrict__ W,
                                          const float* __restrict__ bias,
                                          void* __restrict__ out,
                                          float scale, int m0, int n0) {
  constexpr int BN = NF * 32;
  __shared__ __align__(16) bf16 As[128 * 32];
  __shared__ __align__(16) bf16 Bs[BN * 32];
  const int tid  = threadIdx.x;
  const int lane = tid & 63, w = tid >> 6;
  const int l15 = lane & 15, l4 = lane >> 4;
  const int wr = w >> 1, wc = w & 1;
  const int srow = w * 16 + (lane >> 2);
  const int scol = (lane & 3) * 8;

  f32x4 acc[4][NF] = {};
  const bf16* ag = X + (size_t)m0 * DIM;
  const bf16* bg = W + (size_t)n0 * DIM;

  for (int kt = 0; kt < DIM / 32; ++kt) {
    const int k0 = kt * 32;
#pragma unroll
    for (int j = 0; j < 2; ++j) {
      const int row = j * 64 + srow;
      __builtin_amdgcn_global_load_lds(AS1C(ag + (size_t)row * DIM + k0 + scol),
                                       AS3P(As + (j * 64 + w * 16) * 32), 16, 0, 0);
      if (j * 64 < BN)
        __builtin_amdgcn_global_load_lds(AS1C(bg + (size_t)row * DIM + k0 + scol),
                                         AS3P(Bs + (j * 64 + w * 16) * 32), 16, 0, 0);
    }
    __syncthreads();
    bf16x8 af[4], bfr[NF];
#pragma unroll
    for (int m = 0; m < 4; ++m)
      af[m] = *(const bf16x8*)(As + (wr * 64 + m * 16 + l15) * 32 + l4 * 8);
#pragma unroll
    for (int n = 0; n < NF; ++n)
      bfr[n] = *(const bf16x8*)(Bs + (wc * NF * 16 + n * 16 + l15) * 32 + l4 * 8);
#pragma unroll
    for (int m = 0; m < 4; ++m)
#pragma unroll
      for (int n = 0; n < NF; ++n)
        acc[m][n] = mfma16(af[m], bfr[n], acc[m][n]);
    __syncthreads();
  }

#pragma unroll
  for (int m = 0; m < 4; ++m) {
    const int r0 = m0 + wr * 64 + m * 16 + l4 * 4;
#pragma unroll
    for (int n = 0; n < NF; ++n) {
      const int c = n0 + wc * NF * 16 + n * 16 + l15;
      const float bc = bias[c];
#pragma unroll
      for (int t = 0; t < 4; ++t) {
        const float y = (acc[m][n][t] + bc) * scale;
        if constexpr (F32OUT)
          ((float*)out)[(size_t)(r0 + t) * DIM + c] = y;
        else
          ((bf16*)out)[(size_t)(r0 + t) * DIM + c] = (bf16)y;
      }
    }
  }
}

__global__ __launch_bounds__(256) void k_gemm_qkv(
    const bf16* __restrict__ xb, const bf16* __restrict__ weff,
    const float* __restrict__ bq, const float* __restrict__ bk,
    const float* __restrict__ bv,
    bf16* __restrict__ q, bf16* __restrict__ k, bf16* __restrict__ v) {
  const int z = blockIdx.z;
  const bf16* W = weff + (size_t)z * DIM * DIM;
  const float* bias = (z == 0) ? bq : (z == 1) ? bk : bv;
  bf16* out = (z == 0) ? q : (z == 1) ? k : v;
  const float scale = (z == 0) ? 0.125f : 1.0f;
  gemm_body<4, false>(xb, W, bias, out, scale, blockIdx.y * 128, blockIdx.x * 128);
}

__global__ __launch_bounds__(256) void k_gemm_o(
    const bf16* __restrict__ ctx, const bf16* __restrict__ weffo,
    const float* __restrict__ bo, float* __restrict__ out) {
  gemm_body<2, true>(ctx, weffo, bo, out, 1.0f, blockIdx.y * 128, blockIdx.x * 64);
}

// ---------------- K/V fragment pre-pass ----------------
__global__ __launch_bounds__(256) void k_vfrag(const bf16* __restrict__ v,
                                               const bf16* __restrict__ k,
                                               bf16* __restrict__ vf,
                                               bf16* __restrict__ kf) {
  const int lt = blockIdx.x, bh = blockIdx.y;
  const int b = bh >> 4, h = bh & 15;
  __shared__ __align__(16) bf16 tile[64][72];
  const int tid = threadIdx.x;
  const int r = tid >> 2, c0 = (tid & 3) * 16;
  const bf16* src = v + (size_t)(b * LSEQ + lt * 64) * DIM + h * HD;
  *(bf16x8*)(&tile[r][c0])     = *(const bf16x8*)(src + (size_t)r * DIM + c0);
  *(bf16x8*)(&tile[r][c0 + 8]) = *(const bf16x8*)(src + (size_t)r * DIM + c0 + 8);
  __syncthreads();
  const int w = tid >> 6, lane = tid & 63, l31 = lane & 31, hi = lane >> 5;
  {
    const int tt = w >> 1, n = w & 1;
    const int t = lt * 2 + tt;
#pragma unroll
    for (int c = 0; c < 2; ++c) {
      bf16 tmp[8];
#pragma unroll
      for (int j = 0; j < 8; ++j)
        tmp[j] = tile[tt * 32 + c * 16 + hi * 8 + j][n * 32 + l31];
      *(bf16x8*)(vf + ((((size_t)bh * 64 + t) * 4 + n * 2 + c) * 64 + lane) * 8) =
          *(bf16x8*)tmp;
    }
  }
  {
    const int t = lt * 2 + (w & 1);
    const bf16* krow = k + (size_t)(b * LSEQ + t * 32 + l31) * DIM + h * HD + hi * 8;
#pragma unroll
    for (int cc = 0; cc < 2; ++cc) {
      const int c = (w >> 1) + cc * 2;
      *(bf16x8*)(kf + ((((size_t)bh * 64 + t) * 4 + c) * 64 + lane) * 8) =
          *(const bf16x8*)(krow + c * 16);
    }
  }
}

// ---------------- flash attention: 2 q-subs x 2 k-halves per block ----------------
// grid (32, 32): x = 64-row q-tile, y: b = y&1, h = y>>1. 4 blocks/CU, 4 waves/SIMD.
// Wave w: qs = w&1 (32 q-rows), kh = w>>1 (1024-wide k-range, 32 steps).
// Bias double-buffered in LDS via glds; K/V single-buffered regs (L2-resident).
// Issue order K,V then bias(t+1) so vmcnt(4) never drains the fresh bias batch.
__global__ __launch_bounds__(256, 4) void k_attn(
    const bf16* __restrict__ q, const bf16* __restrict__ kf,
    const bf16* __restrict__ vf, const float* __restrict__ bias,
    bf16* __restrict__ ctx) {
  const int tid = threadIdx.x, w = tid >> 6, lane = tid & 63;
  const int l31 = lane & 31, hi = lane >> 5;
  const int qs = w & 1, kh = w >> 1;
  const int b = blockIdx.y & 1, h = blockIdx.y >> 1;
  const int bh = b * NH + h;
  const int q0 = blockIdx.x * 64 + qs * 32;

  __shared__ __align__(16) float blds[4][2][1024];   // 32 KB

  const bf16* qrow = q + (size_t)(b * LSEQ + q0 + l31) * DIM + h * HD;
  bf16x8 Qf[4];
#pragma unroll
  for (int c = 0; c < 4; ++c) Qf[c] = *(const bf16x8*)(qrow + c * 16 + hi * 8);

  const bf16x8* kfp = (const bf16x8*)kf + (size_t)bh * 256 * 64 + lane;
  const bf16x8* vfp = (const bf16x8*)vf + (size_t)bh * 256 * 64 + lane;

  const int lr = lane >> 3, lc = lane & 7;
  const float* bsrc = bias + ((size_t)h * LSEQ + q0 + lr) * LSEQ + kh * 1024 + 4 * (lc ^ lr);

  const unsigned bofs = (unsigned)(uintptr_t)AS3P(&blds[w][0][0]);
  const int sw = (l31 & 7) << 2;
  const unsigned dro0 = 4u * (unsigned)(l31 * 32 + ((hi << 2) ^ sw));

  f32x16 acc0 = {}, acc1 = {};
  float mrun = -3e38f, lrun = 0.f;
  const int T0 = kh * 32;
  bf16x8 Kf[4], Vf[2][2];

#define GLDSB(t_, s_)                                                        \
  { const float* bp_ = bsrc + (size_t)(t_) * 32;                             \
    _Pragma("unroll") for (int g_ = 0; g_ < 4; ++g_)                         \
      __builtin_amdgcn_global_load_lds(AS1C(bp_ + (size_t)g_ * 8 * LSEQ),    \
                                       AS3P(&blds[w][s_][g_ * 256]), 16, 0, 0); }

  auto step = [&](int slot) {
    const unsigned so = bofs + (unsigned)slot * 4096u;
    f32x4 r0, r1, r2, r3;
    asm volatile(
        "ds_read_b128 %0, %4\n\t"
        "ds_read_b128 %1, %5\n\t"
        "ds_read_b128 %2, %6\n\t"
        "ds_read_b128 %3, %7"
        : "=&v"(r0), "=&v"(r1), "=&v"(r2), "=&v"(r3)
        : "v"(so + dro0), "v"(so + (dro0 ^ 32u)), "v"(so + (dro0 ^ 64u)),
          "v"(so + (dro0 ^ 96u)));
    f32x16 s = {};
#pragma unroll
    for (int c = 0; c < 4; ++c) s = mfma32(Kf[c], Qf[c], s);
    asm volatile("s_waitcnt lgkmcnt(0)"
                 : "+v"(r0), "+v"(r1), "+v"(r2), "+v"(r3));
    SB0;
    f32x4 br[4] = {r0, r1, r2, r3};
    float p[16];
#pragma unroll
    for (int r = 0; r < 16; ++r) p[r] = s[r] + br[r >> 2][r & 3];
    float m8[8];
#pragma unroll
    for (int i = 0; i < 8; ++i) m8[i] = fmaxf(p[i], p[i + 8]);
    float tm = fmaxf(fmaxf(fmaxf(m8[0], m8[4]), fmaxf(m8[1], m8[5])),
                     fmaxf(fmaxf(m8[2], m8[6]), fmaxf(m8[3], m8[7])));
    tm = fmaxf(tm, __shfl_xor(tm, 32));
    if (!__all(tm <= mrun + 8.0f)) {   // defer-max (T13)
      const float mn = fmaxf(mrun, tm);
      const float scl = __expf(mrun - mn);
      mrun = mn;
      lrun *= scl;
#pragma unroll
      for (int r = 0; r < 16; ++r) { acc0[r] *= scl; acc1[r] *= scl; }
    }
#pragma unroll
    for (int r = 0; r < 16; ++r) p[r] = __expf(p[r] - mrun);
    float s8[8];
#pragma unroll
    for (int i = 0; i < 8; ++i) s8[i] = p[i] + p[i + 8];
    float rs = ((s8[0] + s8[1]) + (s8[2] + s8[3])) + ((s8[4] + s8[5]) + (s8[6] + s8[7]));
    rs += __shfl_xor(rs, 32);
    lrun += rs;
#pragma unroll
    for (int c = 0; c < 2; ++c) {
      const int c8 = c * 8;
      const int A0 = pk2(p[c8 + 0], p[c8 + 1]);
      const int A1 = pk2(p[c8 + 2], p[c8 + 3]);
      const int B0 = pk2(p[c8 + 4], p[c8 + 5]);
      const int B1 = pk2(p[c8 + 6], p[c8 + 7]);
      const int pA0 = __shfl_xor(A0, 32), pA1 = __shfl_xor(A1, 32);
      const int pB0 = __shfl_xor(B0, 32), pB1 = __shfl_xor(B1, 32);
      i32x4 fi;
      fi[0] = hi ? pB0 : A0;
      fi[1] = hi ? pB1 : A1;
      fi[2] = hi ? B0 : pA0;
      fi[3] = hi ? B1 : pA1;
      const bf16x8 pf = __builtin_bit_cast(bf16x8, fi);
      acc0 = mfma32(Vf[0][c], pf, acc0);
      acc1 = mfma32(Vf[1][c], pf, acc1);
    }
  };

  GLDSB(0, 0); SB0;
  for (int t = 0; t < 32; ++t) {
    const int ts = T0 + t;
#pragma unroll
    for (int c = 0; c < 4; ++c) Kf[c] = kfp[(ts * 4 + c) * 64];
#pragma unroll
    for (int u = 0; u < 4; ++u) Vf[u >> 1][u & 1] = vfp[(ts * 4 + u) * 64];
    SB0;
    { const int tn = (t + 1 > 31) ? 31 : t + 1; GLDSB(tn, (t + 1) & 1); }
    SB0;
    asm volatile("s_waitcnt vmcnt(4)" ::: "memory");
    step(t & 1);
  }
#undef GLDSB

  // ---- merge the two k-halves ----
  asm volatile("s_waitcnt vmcnt(0)" ::: "memory");
  __syncthreads();
  float* mb = (float*)blds;
  if (kh == 1) {
    float* dst = mb + qs * 2304 + lane * 36;
#pragma unroll
    for (int r4 = 0; r4 < 4; ++r4) {
      f32x4 t0 = {acc0[r4 * 4 + 0], acc0[r4 * 4 + 1], acc0[r4 * 4 + 2], acc0[r4 * 4 + 3]};
      *(f32x4*)(dst + r4 * 4) = t0;
      f32x4 t1 = {acc1[r4 * 4 + 0], acc1[r4 * 4 + 1], acc1[r4 * 4 + 2], acc1[r4 * 4 + 3]};
      *(f32x4*)(dst + 16 + r4 * 4) = t1;
    }
    mb[4608 + qs * 128 + lane * 2]     = mrun;
    mb[4608 + qs * 128 + lane * 2 + 1] = lrun;
  }
  __syncthreads();
  if (kh == 0) {
    const float* src = mb + qs * 2304 + lane * 36;
    const float om = mb[4608 + qs * 128 + lane * 2];
    const float ol = mb[4608 + qs * 128 + lane * 2 + 1];
    const float mm = fmaxf(mrun, om);
    const float e0 = __expf(mrun - mm), e1 = __expf(om - mm);
    const float linv = 1.0f / (lrun * e0 + ol * e1);
    bf16* cp = ctx + (size_t)(b * LSEQ + q0 + l31) * DIM + h * HD;
#pragma unroll
    for (int r = 0; r < 16; ++r) {
      const int dr = (r & 3) + 8 * (r >> 2) + 4 * hi;
      cp[dr]      = (bf16)((acc0[r] * e0 + src[r] * e1) * linv);
      cp[32 + dr] = (bf16)((acc1[r] * e0 + src[16 + r] * e1) * linv);
    }
  }
}

// ---------------- launcher ----------------
extern "C" void kernel_launch(void* const* d_in, const int* in_sizes, int n_in,
                              void* d_out, int out_size, void* d_ws, size_t ws_size,
                              hipStream_t stream) {
  const float* x  = (const float*)d_in[0];
  const float* ab = (const float*)d_in[1];
  const float* Wq = (const float*)d_in[2];  const float* bq = (const float*)d_in[3];
  const float* Aq = (const float*)d_in[4];  const float* Bq = (const float*)d_in[5];
  const float* Wk = (const float*)d_in[6];  const float* bk = (const float*)d_in[7];
  const float* Ak = (const float*)d_in[8];  const float* Bk = (const float*)d_in[9];
  const float* Wv = (const float*)d_in[10]; const float* bv = (const float*)d_in[11];
  const float* Av = (const float*)d_in[12]; const float* Bv = (const float*)d_in[13];
  const float* Wo = (const float*)d_in[14]; const float* bo = (const float*)d_in[15];
  const float* Ao = (const float*)d_in[16]; const float* Bo = (const float*)d_in[17];

  uint8_t* ws = (uint8_t*)d_ws;
  const size_t SZ = (size_t)NTOK * DIM * sizeof(bf16);  // 8 MiB
  bf16* xb   = (bf16*)(ws + 0 * SZ);
  bf16* weff = (bf16*)(ws + 1 * SZ);
  bf16* qb   = (bf16*)(ws + 2 * SZ);
  bf16* kb   = (bf16*)(ws + 3 * SZ);
  bf16* vb   = (bf16*)(ws + 4 * SZ);
  bf16* kfb  = (bf16*)(ws + 5 * SZ);
  bf16* vfb  = (bf16*)(ws + 6 * SZ);
  bf16* ctx  = (bf16*)(ws + 7 * SZ);

  k_cvt<<<dim3(NTOK * DIM / 1024), 256, 0, stream>>>(x, xb);

  WeffArgs wa;
  wa.W[0] = Wq; wa.A[0] = Aq; wa.B[0] = Bq; wa.out[0] = weff;
  wa.W[1] = Wk; wa.A[1] = Ak; wa.B[1] = Bk; wa.out[1] = weff + (size_t)DIM * DIM;
  wa.W[2] = Wv; wa.A[2] = Av; wa.B[2] = Bv; wa.out[2] = weff + 2 * (size_t)DIM * DIM;
  wa.W[3] = Wo; wa.A[3] = Ao; wa.B[3] = Bo; wa.out[3] = weff + 3 * (size_t)DIM * DIM;
  k_weff<<<dim3(DIM, 4), 256, 0, stream>>>(wa);

  k_gemm_qkv<<<dim3(8, 32, 3), 256, 0, stream>>>(xb, weff, bq, bk, bv, qb, kb, vb);
  k_vfrag<<<dim3(32, 32), 256, 0, stream>>>(vb, kb, vfb, kfb);
  k_attn<<<dim3(32, 32), 256, 0, stream>>>(qb, kfb, vfb, ab, ctx);
  k_gemm_o<<<dim3(16, 32), 256, 0, stream>>>(ctx, weff + 3 * (size_t)DIM * DIM, bo,
                                             (float*)d_out);
}

// Round 6
// 184.360 us; speedup vs baseline: 2.8705x; 1.1215x over previous
//
#include <hip/hip_runtime.h>
#include <cstdint>

typedef __bf16 bf16;
typedef __bf16 bf16x8 __attribute__((ext_vector_type(8)));
typedef __bf16 bf16x4 __attribute__((ext_vector_type(4)));
typedef float  f32x4  __attribute__((ext_vector_type(4)));
typedef float  f32x16 __attribute__((ext_vector_type(16)));
typedef int    i32x4  __attribute__((ext_vector_type(4)));

#define DIM   1024
#define LSEQ  2048
#define NH    16
#define HD    64
#define NTOK  4096

#define AS1C(p) ((const __attribute__((address_space(1))) void*)(unsigned long long)(uintptr_t)(p))
#define AS3P(p) ((__attribute__((address_space(3))) void*)(unsigned int)(uintptr_t)(p))
#define SB0 __builtin_amdgcn_sched_barrier(0)

__device__ __forceinline__ f32x4 mfma16(bf16x8 a, bf16x8 b, f32x4 c) {
  return __builtin_amdgcn_mfma_f32_16x16x32_bf16(a, b, c, 0, 0, 0);
}
__device__ __forceinline__ f32x16 mfma32(bf16x8 a, bf16x8 b, f32x16 c) {
  return __builtin_amdgcn_mfma_f32_32x32x16_bf16(a, b, c, 0, 0, 0);
}
__device__ __forceinline__ int pk2(float a, float b) {
  unsigned short ua = __builtin_bit_cast(unsigned short, (bf16)a);
  unsigned short ub = __builtin_bit_cast(unsigned short, (bf16)b);
  return (int)ua | ((int)ub << 16);
}

// ---------------- x (fp32) -> bf16 ----------------
__global__ __launch_bounds__(256) void k_cvt(const float* __restrict__ x,
                                             bf16* __restrict__ xb) {
  const int i = (blockIdx.x * 256 + threadIdx.x) * 4;
  const f32x4 v = *(const f32x4*)(x + i);
  bf16x4 o;
  o[0] = (bf16)v[0]; o[1] = (bf16)v[1]; o[2] = (bf16)v[2]; o[3] = (bf16)v[3];
  *(bf16x4*)(xb + i) = o;
}

// ---------------- W_eff[o][d] = W[o][d] + 0.5 * sum_r A[d][r] * B[r][o] ----------------
struct WeffArgs {
  const float* W[4]; const float* A[4]; const float* B[4]; bf16* out[4];
};

__global__ __launch_bounds__(256) void k_weff(WeffArgs args) {
  const int o = blockIdx.x;
  const int z = blockIdx.y;
  const float* __restrict__ W  = args.W[z];
  const float* __restrict__ A  = args.A[z];
  const float* __restrict__ Bm = args.B[z];
  bf16* __restrict__ out = args.out[z];
  float Bo[16];
#pragma unroll
  for (int r = 0; r < 16; ++r) Bo[r] = Bm[r * DIM + o];
#pragma unroll
  for (int j = 0; j < 4; ++j) {
    const int d = j * 256 + (int)threadIdx.x;
    const float* Ar = A + (size_t)d * 16;
    float acc = 0.f;
#pragma unroll
    for (int r = 0; r < 16; ++r) acc += Ar[r] * Bo[r];
    out[(size_t)o * DIM + d] = (bf16)(W[(size_t)o * DIM + d] + 0.5f * acc);
  }
}

// ---------------- GEMM (m97 structure), BN = NF*32 ----------------
template <int NF, bool F32OUT>
__device__ __forceinline__ void gemm_body(const bf16* __restrict__ X,
                                          const bf16* __restrict__ W,
                                          const float* __restrict__ bias,
                                          void* __restrict__ out,
                                          float scale, int m0, int n0) {
  constexpr int BN = NF * 32;
  __shared__ __align__(16) bf16 As[128 * 32];
  __shared__ __align__(16) bf16 Bs[BN * 32];
  const int tid  = threadIdx.x;
  const int lane = tid & 63, w = tid >> 6;
  const int l15 = lane & 15, l4 = lane >> 4;
  const int wr = w >> 1, wc = w & 1;
  const int srow = w * 16 + (lane >> 2);
  const int scol = (lane & 3) * 8;

  f32x4 acc[4][NF] = {};
  const bf16* ag = X + (size_t)m0 * DIM;
  const bf16* bg = W + (size_t)n0 * DIM;

  for (int kt = 0; kt < DIM / 32; ++kt) {
    const int k0 = kt * 32;
#pragma unroll
    for (int j = 0; j < 2; ++j) {
      const int row = j * 64 + srow;
      __builtin_amdgcn_global_load_lds(AS1C(ag + (size_t)row * DIM + k0 + scol),
                                       AS3P(As + (j * 64 + w * 16) * 32), 16, 0, 0);
      if (j * 64 < BN)
        __builtin_amdgcn_global_load_lds(AS1C(bg + (size_t)row * DIM + k0 + scol),
                                         AS3P(Bs + (j * 64 + w * 16) * 32), 16, 0, 0);
    }
    __syncthreads();
    bf16x8 af[4], bfr[NF];
#pragma unroll
    for (int m = 0; m < 4; ++m)
      af[m] = *(const bf16x8*)(As + (wr * 64 + m * 16 + l15) * 32 + l4 * 8);
#pragma unroll
    for (int n = 0; n < NF; ++n)
      bfr[n] = *(const bf16x8*)(Bs + (wc * NF * 16 + n * 16 + l15) * 32 + l4 * 8);
#pragma unroll
    for (int m = 0; m < 4; ++m)
#pragma unroll
      for (int n = 0; n < NF; ++n)
        acc[m][n] = mfma16(af[m], bfr[n], acc[m][n]);
    __syncthreads();
  }

#pragma unroll
  for (int m = 0; m < 4; ++m) {
    const int r0 = m0 + wr * 64 + m * 16 + l4 * 4;
#pragma unroll
    for (int n = 0; n < NF; ++n) {
      const int c = n0 + wc * NF * 16 + n * 16 + l15;
      const float bc = bias[c];
#pragma unroll
      for (int t = 0; t < 4; ++t) {
        const float y = (acc[m][n][t] + bc) * scale;
        if constexpr (F32OUT)
          ((float*)out)[(size_t)(r0 + t) * DIM + c] = y;
        else
          ((bf16*)out)[(size_t)(r0 + t) * DIM + c] = (bf16)y;
      }
    }
  }
}

__global__ __launch_bounds__(256) void k_gemm_qkv(
    const bf16* __restrict__ xb, const bf16* __restrict__ weff,
    const float* __restrict__ bq, const float* __restrict__ bk,
    const float* __restrict__ bv,
    bf16* __restrict__ q, bf16* __restrict__ k, bf16* __restrict__ v) {
  const int z = blockIdx.z;
  const bf16* W = weff + (size_t)z * DIM * DIM;
  const float* bias = (z == 0) ? bq : (z == 1) ? bk : bv;
  bf16* out = (z == 0) ? q : (z == 1) ? k : v;
  const float scale = (z == 0) ? 0.125f : 1.0f;
  gemm_body<4, false>(xb, W, bias, out, scale, blockIdx.y * 128, blockIdx.x * 128);
}

__global__ __launch_bounds__(256) void k_gemm_o(
    const bf16* __restrict__ ctx, const bf16* __restrict__ weffo,
    const float* __restrict__ bo, float* __restrict__ out) {
  gemm_body<2, true>(ctx, weffo, bo, out, 1.0f, blockIdx.y * 128, blockIdx.x * 64);
}

// ---------------- K/V fragment pre-pass ----------------
// kf[bh][t][c][lane] (bf16x8): K[t*32+l31][h*64 + c*16 + hi*8 + j]
// vf[bh][t][n*2+c][lane]     : V^T[n*32+l31][t*32 + c*16 + hi*8 + j]
__global__ __launch_bounds__(256) void k_vfrag(const bf16* __restrict__ v,
                                               const bf16* __restrict__ k,
                                               bf16* __restrict__ vf,
                                               bf16* __restrict__ kf) {
  const int lt = blockIdx.x, bh = blockIdx.y;
  const int b = bh >> 4, h = bh & 15;
  __shared__ __align__(16) bf16 tile[64][72];
  const int tid = threadIdx.x;
  const int r = tid >> 2, c0 = (tid & 3) * 16;
  const bf16* src = v + (size_t)(b * LSEQ + lt * 64) * DIM + h * HD;
  *(bf16x8*)(&tile[r][c0])     = *(const bf16x8*)(src + (size_t)r * DIM + c0);
  *(bf16x8*)(&tile[r][c0 + 8]) = *(const bf16x8*)(src + (size_t)r * DIM + c0 + 8);
  __syncthreads();
  const int w = tid >> 6, lane = tid & 63, l31 = lane & 31, hi = lane >> 5;
  {
    const int tt = w >> 1, n = w & 1;
    const int t = lt * 2 + tt;
#pragma unroll
    for (int c = 0; c < 2; ++c) {
      bf16 tmp[8];
#pragma unroll
      for (int j = 0; j < 8; ++j)
        tmp[j] = tile[tt * 32 + c * 16 + hi * 8 + j][n * 32 + l31];
      *(bf16x8*)(vf + ((((size_t)bh * 64 + t) * 4 + n * 2 + c) * 64 + lane) * 8) =
          *(bf16x8*)tmp;
    }
  }
  {
    const int t = lt * 2 + (w & 1);
    const bf16* krow = k + (size_t)(b * LSEQ + t * 32 + l31) * DIM + h * HD + hi * 8;
#pragma unroll
    for (int cc = 0; cc < 2; ++cc) {
      const int c = (w >> 1) + cc * 2;
      *(bf16x8*)(kf + ((((size_t)bh * 64 + t) * 4 + c) * 64 + lane) * 8) =
          *(const bf16x8*)(krow + c * 16);
    }
  }
}

// ---------------- flash attention: fully glds-pipelined ----------------
// grid (16, 32): x = 128-row q-tile (4 waves x 32 q-rows), y: b=y&1, h=y>>1.
// All 4 waves walk the full k range together; per step, K(4KB)+V(4KB) shared
// and bias(4KB/wave) are staged into LDS via global_load_lds, 3 slots,
// 2 steps ahead. Counted vmcnt(12) (2 stages x 6 glds/wave in flight); raw
// s_barrier pairs per step (8-phase discipline). LDS 72KB -> 2 blocks/CU.
__global__ __launch_bounds__(256, 2) void k_attn(
    const bf16* __restrict__ q, const bf16* __restrict__ kf,
    const bf16* __restrict__ vf, const float* __restrict__ bias,
    bf16* __restrict__ ctx) {
  const int tid = threadIdx.x, w = tid >> 6, lane = tid & 63;
  const int l31 = lane & 31, hi = lane >> 5;
  const int b = blockIdx.y & 1, h = blockIdx.y >> 1;
  const int bh = b * NH + h;
  const int q0 = blockIdx.x * 128 + w * 32;

  __shared__ __align__(16) bf16  kls[3][2048];      // 12 KB
  __shared__ __align__(16) bf16  vls[3][2048];      // 12 KB
  __shared__ __align__(16) float bls[4][3][1024];   // 48 KB

  const bf16* qrow = q + (size_t)(b * LSEQ + q0 + l31) * DIM + h * HD;
  bf16x8 Qf[4];
#pragma unroll
  for (int c = 0; c < 4; ++c) Qf[c] = *(const bf16x8*)(qrow + c * 16 + hi * 8);

  const bf16* kfb = kf + (size_t)bh * 64 * 2048 + w * 512 + lane * 8;
  const bf16* vfb = vf + (size_t)bh * 64 * 2048 + w * 512 + lane * 8;
  const int lr = lane >> 3, lc = lane & 7;
  const float* bsrc = bias + ((size_t)h * LSEQ + q0 + lr) * LSEQ + 4 * (lc ^ lr);

  f32x16 acc0 = {}, acc1 = {};
  float mrun = -3e38f, lrun = 0.f;

#define STAGE(ts_, s_)                                                         \
  {                                                                            \
    __builtin_amdgcn_global_load_lds(AS1C(kfb + (size_t)(ts_) * 2048),         \
                                     AS3P(&kls[s_][w * 512]), 16, 0, 0);       \
    __builtin_amdgcn_global_load_lds(AS1C(vfb + (size_t)(ts_) * 2048),         \
                                     AS3P(&vls[s_][w * 512]), 16, 0, 0);       \
    const float* bp_ = bsrc + (size_t)(ts_) * 32;                              \
    _Pragma("unroll") for (int g_ = 0; g_ < 4; ++g_)                           \
        __builtin_amdgcn_global_load_lds(AS1C(bp_ + (size_t)g_ * 8 * LSEQ),    \
                                         AS3P(&bls[w][s_][g_ * 256]), 16, 0, 0); \
  }

  STAGE(0, 0); SB0;
  STAGE(1, 1); SB0;

  int sl = 0, ss = 2;  // read slot, stage slot
  for (int t = 0; t < 64; ++t) {
    const int tn = (t + 2 > 63) ? 63 : t + 2;
    STAGE(tn, ss); SB0;
    asm volatile("s_waitcnt vmcnt(12)" ::: "memory");
    __builtin_amdgcn_s_barrier();   // slot sl fully staged (all waves waited)

    bf16x8 Kf[4], Vf[2][2];
    f32x4 br[4];
#pragma unroll
    for (int c = 0; c < 4; ++c)
      Kf[c] = *(const bf16x8*)(&kls[sl][(c * 64 + lane) * 8]);
#pragma unroll
    for (int u = 0; u < 4; ++u)
      Vf[u >> 1][u & 1] = *(const bf16x8*)(&vls[sl][(u * 64 + lane) * 8]);
#pragma unroll
    for (int g = 0; g < 4; ++g)
      br[g] = *(const f32x4*)(
          &bls[w][sl][l31 * 32 + (((g << 3) | (hi << 2)) ^ ((l31 & 7) << 2))]);
    asm volatile("s_waitcnt lgkmcnt(0)" ::: "memory");
    SB0;
    __builtin_amdgcn_s_barrier();   // reads done: slot sl may be overwritten

    // ---- compute step t ----
    f32x16 s = {};
#pragma unroll
    for (int c = 0; c < 4; ++c) s = mfma32(Kf[c], Qf[c], s);
    float p[16];
#pragma unroll
    for (int r = 0; r < 16; ++r) p[r] = s[r] + br[r >> 2][r & 3];
    float m8[8];
#pragma unroll
    for (int i = 0; i < 8; ++i) m8[i] = fmaxf(p[i], p[i + 8]);
    float tm = fmaxf(fmaxf(fmaxf(m8[0], m8[4]), fmaxf(m8[1], m8[5])),
                     fmaxf(fmaxf(m8[2], m8[6]), fmaxf(m8[3], m8[7])));
    tm = fmaxf(tm, __shfl_xor(tm, 32));
    if (!__all(tm <= mrun + 8.0f)) {   // defer-max (T13)
      const float mn = fmaxf(mrun, tm);
      const float scl = __expf(mrun - mn);
      mrun = mn;
      lrun *= scl;
#pragma unroll
      for (int r = 0; r < 16; ++r) { acc0[r] *= scl; acc1[r] *= scl; }
    }
#pragma unroll
    for (int r = 0; r < 16; ++r) p[r] = __expf(p[r] - mrun);
    float s8[8];
#pragma unroll
    for (int i = 0; i < 8; ++i) s8[i] = p[i] + p[i + 8];
    float rs = ((s8[0] + s8[1]) + (s8[2] + s8[3])) + ((s8[4] + s8[5]) + (s8[6] + s8[7]));
    rs += __shfl_xor(rs, 32);
    lrun += rs;
#pragma unroll
    for (int c = 0; c < 2; ++c) {
      const int c8 = c * 8;
      const int A0 = pk2(p[c8 + 0], p[c8 + 1]);
      const int A1 = pk2(p[c8 + 2], p[c8 + 3]);
      const int B0 = pk2(p[c8 + 4], p[c8 + 5]);
      const int B1 = pk2(p[c8 + 6], p[c8 + 7]);
      const int pA0 = __shfl_xor(A0, 32), pA1 = __shfl_xor(A1, 32);
      const int pB0 = __shfl_xor(B0, 32), pB1 = __shfl_xor(B1, 32);
      i32x4 fi;
      fi[0] = hi ? pB0 : A0;
      fi[1] = hi ? pB1 : A1;
      fi[2] = hi ? B0 : pA0;
      fi[3] = hi ? B1 : pA1;
      const bf16x8 pf = __builtin_bit_cast(bf16x8, fi);
      acc0 = mfma32(Vf[0][c], pf, acc0);
      acc1 = mfma32(Vf[1][c], pf, acc1);
    }
    sl = (sl == 2) ? 0 : sl + 1;
    ss = (ss == 2) ? 0 : ss + 1;
  }
#undef STAGE

  const float inv = 1.0f / lrun;
  bf16* cp = ctx + (size_t)(b * LSEQ + q0 + l31) * DIM + h * HD;
#pragma unroll
  for (int r = 0; r < 16; ++r) {
    const int dr = (r & 3) + 8 * (r >> 2) + 4 * hi;
    cp[dr]      = (bf16)(acc0[r] * inv);
    cp[32 + dr] = (bf16)(acc1[r] * inv);
  }
}

// ---------------- launcher ----------------
extern "C" void kernel_launch(void* const* d_in, const int* in_sizes, int n_in,
                              void* d_out, int out_size, void* d_ws, size_t ws_size,
                              hipStream_t stream) {
  const float* x  = (const float*)d_in[0];
  const float* ab = (const float*)d_in[1];
  const float* Wq = (const float*)d_in[2];  const float* bq = (const float*)d_in[3];
  const float* Aq = (const float*)d_in[4];  const float* Bq = (const float*)d_in[5];
  const float* Wk = (const float*)d_in[6];  const float* bk = (const float*)d_in[7];
  const float* Ak = (const float*)d_in[8];  const float* Bk = (const float*)d_in[9];
  const float* Wv = (const float*)d_in[10]; const float* bv = (const float*)d_in[11];
  const float* Av = (const float*)d_in[12]; const float* Bv = (const float*)d_in[13];
  const float* Wo = (const float*)d_in[14]; const float* bo = (const float*)d_in[15];
  const float* Ao = (const float*)d_in[16]; const float* Bo = (const float*)d_in[17];

  uint8_t* ws = (uint8_t*)d_ws;
  const size_t SZ = (size_t)NTOK * DIM * sizeof(bf16);  // 8 MiB
  bf16* xb   = (bf16*)(ws + 0 * SZ);
  bf16* weff = (bf16*)(ws + 1 * SZ);
  bf16* qb   = (bf16*)(ws + 2 * SZ);
  bf16* kb   = (bf16*)(ws + 3 * SZ);
  bf16* vb   = (bf16*)(ws + 4 * SZ);
  bf16* kfb  = (bf16*)(ws + 5 * SZ);
  bf16* vfb  = (bf16*)(ws + 6 * SZ);
  bf16* ctx  = (bf16*)(ws + 7 * SZ);

  k_cvt<<<dim3(NTOK * DIM / 1024), 256, 0, stream>>>(x, xb);

  WeffArgs wa;
  wa.W[0] = Wq; wa.A[0] = Aq; wa.B[0] = Bq; wa.out[0] = weff;
  wa.W[1] = Wk; wa.A[1] = Ak; wa.B[1] = Bk; wa.out[1] = weff + (size_t)DIM * DIM;
  wa.W[2] = Wv; wa.A[2] = Av; wa.B[2] = Bv; wa.out[2] = weff + 2 * (size_t)DIM * DIM;
  wa.W[3] = Wo; wa.A[3] = Ao; wa.B[3] = Bo; wa.out[3] = weff + 3 * (size_t)DIM * DIM;
  k_weff<<<dim3(DIM, 4), 256, 0, stream>>>(wa);

  k_gemm_qkv<<<dim3(8, 32, 3), 256, 0, stream>>>(xb, weff, bq, bk, bv, qb, kb, vb);
  k_vfrag<<<dim3(32, 32), 256, 0, stream>>>(vb, kb, vfb, kfb);
  k_attn<<<dim3(16, 32), 256, 0, stream>>>(qb, kfb, vfb, ab, ctx);
  k_gemm_o<<<dim3(16, 32), 256, 0, stream>>>(ctx, weff + 3 * (size_t)DIM * DIM, bo,
                                             (float*)d_out);
}

// Round 7
// 183.420 us; speedup vs baseline: 2.8852x; 1.0051x over previous
//
#include <hip/hip_runtime.h>
#include <cstdint>

typedef __bf16 bf16;
typedef __bf16 bf16x8 __attribute__((ext_vector_type(8)));
typedef __bf16 bf16x4 __attribute__((ext_vector_type(4)));
typedef float  f32x4  __attribute__((ext_vector_type(4)));
typedef float  f32x16 __attribute__((ext_vector_type(16)));
typedef int    i32x4  __attribute__((ext_vector_type(4)));

#define DIM   1024
#define LSEQ  2048
#define NH    16
#define HD    64
#define NTOK  4096

#define AS1C(p) ((const __attribute__((address_space(1))) void*)(unsigned long long)(uintptr_t)(p))
#define AS3P(p) ((__attribute__((address_space(3))) void*)(unsigned int)(uintptr_t)(p))
#define SB0 __builtin_amdgcn_sched_barrier(0)

__device__ __forceinline__ f32x4 mfma16(bf16x8 a, bf16x8 b, f32x4 c) {
  return __builtin_amdgcn_mfma_f32_16x16x32_bf16(a, b, c, 0, 0, 0);
}
__device__ __forceinline__ f32x16 mfma32(bf16x8 a, bf16x8 b, f32x16 c) {
  return __builtin_amdgcn_mfma_f32_32x32x16_bf16(a, b, c, 0, 0, 0);
}
__device__ __forceinline__ int pk2(float a, float b) {
  unsigned short ua = __builtin_bit_cast(unsigned short, (bf16)a);
  unsigned short ub = __builtin_bit_cast(unsigned short, (bf16)b);
  return (int)ua | ((int)ub << 16);
}

// ---------------- x (fp32) -> bf16 ----------------
__global__ __launch_bounds__(256) void k_cvt(const float* __restrict__ x,
                                             bf16* __restrict__ xb) {
  const int i = (blockIdx.x * 256 + threadIdx.x) * 4;
  const f32x4 v = *(const f32x4*)(x + i);
  bf16x4 o;
  o[0] = (bf16)v[0]; o[1] = (bf16)v[1]; o[2] = (bf16)v[2]; o[3] = (bf16)v[3];
  *(bf16x4*)(xb + i) = o;
}

// ---------------- W_eff[o][d] = W[o][d] + 0.5 * sum_r A[d][r] * B[r][o] ----------------
struct WeffArgs {
  const float* W[4]; const float* A[4]; const float* B[4]; bf16* out[4];
};

__global__ __launch_bounds__(256) void k_weff(WeffArgs args) {
  const int o = blockIdx.x;
  const int z = blockIdx.y;
  const float* __restrict__ W  = args.W[z];
  const float* __restrict__ A  = args.A[z];
  const float* __restrict__ Bm = args.B[z];
  bf16* __restrict__ out = args.out[z];
  float Bo[16];
#pragma unroll
  for (int r = 0; r < 16; ++r) Bo[r] = Bm[r * DIM + o];
#pragma unroll
  for (int j = 0; j < 4; ++j) {
    const int d = j * 256 + (int)threadIdx.x;
    const float* Ar = A + (size_t)d * 16;
    float acc = 0.f;
#pragma unroll
    for (int r = 0; r < 16; ++r) acc += Ar[r] * Bo[r];
    out[(size_t)o * DIM + d] = (bf16)(W[(size_t)o * DIM + d] + 0.5f * acc);
  }
}

// ---------------- GEMM (m97 structure), BN = NF*32 ----------------
template <int NF, bool F32OUT>
__device__ __forceinline__ void gemm_body(const bf16* __restrict__ X,
                                          const bf16* __restrict__ W,
                                          const float* __restrict__ bias,
                                          void* __restrict__ out,
                                          float scale, int m0, int n0) {
  constexpr int BN = NF * 32;
  __shared__ __align__(16) bf16 As[128 * 32];
  __shared__ __align__(16) bf16 Bs[BN * 32];
  const int tid  = threadIdx.x;
  const int lane = tid & 63, w = tid >> 6;
  const int l15 = lane & 15, l4 = lane >> 4;
  const int wr = w >> 1, wc = w & 1;
  const int srow = w * 16 + (lane >> 2);
  const int scol = (lane & 3) * 8;

  f32x4 acc[4][NF] = {};
  const bf16* ag = X + (size_t)m0 * DIM;
  const bf16* bg = W + (size_t)n0 * DIM;

  for (int kt = 0; kt < DIM / 32; ++kt) {
    const int k0 = kt * 32;
#pragma unroll
    for (int j = 0; j < 2; ++j) {
      const int row = j * 64 + srow;
      __builtin_amdgcn_global_load_lds(AS1C(ag + (size_t)row * DIM + k0 + scol),
                                       AS3P(As + (j * 64 + w * 16) * 32), 16, 0, 0);
      if (j * 64 < BN)
        __builtin_amdgcn_global_load_lds(AS1C(bg + (size_t)row * DIM + k0 + scol),
                                         AS3P(Bs + (j * 64 + w * 16) * 32), 16, 0, 0);
    }
    __syncthreads();
    bf16x8 af[4], bfr[NF];
#pragma unroll
    for (int m = 0; m < 4; ++m)
      af[m] = *(const bf16x8*)(As + (wr * 64 + m * 16 + l15) * 32 + l4 * 8);
#pragma unroll
    for (int n = 0; n < NF; ++n)
      bfr[n] = *(const bf16x8*)(Bs + (wc * NF * 16 + n * 16 + l15) * 32 + l4 * 8);
#pragma unroll
    for (int m = 0; m < 4; ++m)
#pragma unroll
      for (int n = 0; n < NF; ++n)
        acc[m][n] = mfma16(af[m], bfr[n], acc[m][n]);
    __syncthreads();
  }

#pragma unroll
  for (int m = 0; m < 4; ++m) {
    const int r0 = m0 + wr * 64 + m * 16 + l4 * 4;
#pragma unroll
    for (int n = 0; n < NF; ++n) {
      const int c = n0 + wc * NF * 16 + n * 16 + l15;
      const float bc = bias[c];
#pragma unroll
      for (int t = 0; t < 4; ++t) {
        const float y = (acc[m][n][t] + bc) * scale;
        if constexpr (F32OUT)
          ((float*)out)[(size_t)(r0 + t) * DIM + c] = y;
        else
          ((bf16*)out)[(size_t)(r0 + t) * DIM + c] = (bf16)y;
      }
    }
  }
}

// grid (32 m, 8 n, 3 z): same-A-panel blocks (fixed x) all land on XCD x%8
// -> A panel L2-pinned (1 MB/XCD working set), A HBM 192MB -> ~8MB.
__global__ __launch_bounds__(256) void k_gemm_qkv(
    const bf16* __restrict__ xb, const bf16* __restrict__ weff,
    const float* __restrict__ bq, const float* __restrict__ bk,
    const float* __restrict__ bv,
    bf16* __restrict__ q, bf16* __restrict__ k, bf16* __restrict__ v) {
  const int z = blockIdx.z;
  const bf16* W = weff + (size_t)z * DIM * DIM;
  const float* bias = (z == 0) ? bq : (z == 1) ? bk : bv;
  bf16* out = (z == 0) ? q : (z == 1) ? k : v;
  const float scale = (z == 0) ? 0.125f : 1.0f;
  gemm_body<4, false>(xb, W, bias, out, scale, blockIdx.x * 128, blockIdx.y * 128);
}

// grid (32 m, 16 n): ctx A-panels L2-pinned per XCD.
__global__ __launch_bounds__(256) void k_gemm_o(
    const bf16* __restrict__ ctx, const bf16* __restrict__ weffo,
    const float* __restrict__ bo, float* __restrict__ out) {
  gemm_body<2, true>(ctx, weffo, bo, out, 1.0f, blockIdx.x * 128, blockIdx.y * 64);
}

// ---------------- K/V fragment pre-pass ----------------
// kf[bh][t][c][lane] (bf16x8): K[t*32+l31][h*64 + c*16 + hi*8 + j]
// vf[bh][t][n*2+c][lane]     : V^T[n*32+l31][t*32 + c*16 + hi*8 + j]
__global__ __launch_bounds__(256) void k_vfrag(const bf16* __restrict__ v,
                                               const bf16* __restrict__ k,
                                               bf16* __restrict__ vf,
                                               bf16* __restrict__ kf) {
  const int lt = blockIdx.x, bh = blockIdx.y;
  const int b = bh >> 4, h = bh & 15;
  __shared__ __align__(16) bf16 tile[64][72];
  const int tid = threadIdx.x;
  const int r = tid >> 2, c0 = (tid & 3) * 16;
  const bf16* src = v + (size_t)(b * LSEQ + lt * 64) * DIM + h * HD;
  *(bf16x8*)(&tile[r][c0])     = *(const bf16x8*)(src + (size_t)r * DIM + c0);
  *(bf16x8*)(&tile[r][c0 + 8]) = *(const bf16x8*)(src + (size_t)r * DIM + c0 + 8);
  __syncthreads();
  const int w = tid >> 6, lane = tid & 63, l31 = lane & 31, hi = lane >> 5;
  {
    const int tt = w >> 1, n = w & 1;
    const int t = lt * 2 + tt;
#pragma unroll
    for (int c = 0; c < 2; ++c) {
      bf16 tmp[8];
#pragma unroll
      for (int j = 0; j < 8; ++j)
        tmp[j] = tile[tt * 32 + c * 16 + hi * 8 + j][n * 32 + l31];
      *(bf16x8*)(vf + ((((size_t)bh * 64 + t) * 4 + n * 2 + c) * 64 + lane) * 8) =
          *(bf16x8*)tmp;
    }
  }
  {
    const int t = lt * 2 + (w & 1);
    const bf16* krow = k + (size_t)(b * LSEQ + t * 32 + l31) * DIM + h * HD + hi * 8;
#pragma unroll
    for (int cc = 0; cc < 2; ++cc) {
      const int c = (w >> 1) + cc * 2;
      *(bf16x8*)(kf + ((((size_t)bh * 64 + t) * 4 + c) * 64 + lane) * 8) =
          *(const bf16x8*)(krow + c * 16);
    }
  }
}

// ---------------- flash attention: fully glds-pipelined ----------------
// grid (32 bh, 16 q): bh = b*16+h fastest -> all 16 q-blocks of a bh AND the
// b=0/b=1 twins (ids differ by 16 = 0 mod 8) land on the same XCD:
// K/V frag slices L2-pinned (2 MB/XCD), bias stream shared by twins via L2.
__global__ __launch_bounds__(256, 2) void k_attn(
    const bf16* __restrict__ q, const bf16* __restrict__ kf,
    const bf16* __restrict__ vf, const float* __restrict__ bias,
    bf16* __restrict__ ctx) {
  const int tid = threadIdx.x, w = tid >> 6, lane = tid & 63;
  const int l31 = lane & 31, hi = lane >> 5;
  const int bh = blockIdx.x;
  const int b = bh >> 4, h = bh & 15;
  const int q0 = blockIdx.y * 128 + w * 32;

  __shared__ __align__(16) bf16  kls[3][2048];      // 12 KB
  __shared__ __align__(16) bf16  vls[3][2048];      // 12 KB
  __shared__ __align__(16) float bls[4][3][1024];   // 48 KB

  const bf16* qrow = q + (size_t)(b * LSEQ + q0 + l31) * DIM + h * HD;
  bf16x8 Qf[4];
#pragma unroll
  for (int c = 0; c < 4; ++c) Qf[c] = *(const bf16x8*)(qrow + c * 16 + hi * 8);

  const bf16* kfb = kf + (size_t)bh * 64 * 2048 + w * 512 + lane * 8;
  const bf16* vfb = vf + (size_t)bh * 64 * 2048 + w * 512 + lane * 8;
  const int lr = lane >> 3, lc = lane & 7;
  const float* bsrc = bias + ((size_t)h * LSEQ + q0 + lr) * LSEQ + 4 * (lc ^ lr);

  f32x16 acc0 = {}, acc1 = {};
  float mrun = -3e38f, lrun = 0.f;

#define STAGE(ts_, s_)                                                         \
  {                                                                            \
    __builtin_amdgcn_global_load_lds(AS1C(kfb + (size_t)(ts_) * 2048),         \
                                     AS3P(&kls[s_][w * 512]), 16, 0, 0);       \
    __builtin_amdgcn_global_load_lds(AS1C(vfb + (size_t)(ts_) * 2048),         \
                                     AS3P(&vls[s_][w * 512]), 16, 0, 0);       \
    const float* bp_ = bsrc + (size_t)(ts_) * 32;                              \
    _Pragma("unroll") for (int g_ = 0; g_ < 4; ++g_)                           \
        __builtin_amdgcn_global_load_lds(AS1C(bp_ + (size_t)g_ * 8 * LSEQ),    \
                                         AS3P(&bls[w][s_][g_ * 256]), 16, 0, 0); \
  }

  STAGE(0, 0); SB0;
  STAGE(1, 1); SB0;

  int sl = 0, ss = 2;  // read slot, stage slot
  for (int t = 0; t < 64; ++t) {
    const int tn = (t + 2 > 63) ? 63 : t + 2;
    STAGE(tn, ss); SB0;
    asm volatile("s_waitcnt vmcnt(12)" ::: "memory");
    __builtin_amdgcn_s_barrier();   // slot sl fully staged (all waves waited)

    bf16x8 Kf[4], Vf[2][2];
    f32x4 br[4];
#pragma unroll
    for (int c = 0; c < 4; ++c)
      Kf[c] = *(const bf16x8*)(&kls[sl][(c * 64 + lane) * 8]);
#pragma unroll
    for (int u = 0; u < 4; ++u)
      Vf[u >> 1][u & 1] = *(const bf16x8*)(&vls[sl][(u * 64 + lane) * 8]);
#pragma unroll
    for (int g = 0; g < 4; ++g)
      br[g] = *(const f32x4*)(
          &bls[w][sl][l31 * 32 + (((g << 3) | (hi << 2)) ^ ((l31 & 7) << 2))]);
    asm volatile("s_waitcnt lgkmcnt(0)" ::: "memory");
    SB0;
    __builtin_amdgcn_s_barrier();   // reads done: slot sl may be overwritten

    // ---- compute step t ----
    f32x16 s = {};
#pragma unroll
    for (int c = 0; c < 4; ++c) s = mfma32(Kf[c], Qf[c], s);
    float p[16];
#pragma unroll
    for (int r = 0; r < 16; ++r) p[r] = s[r] + br[r >> 2][r & 3];
    float m8[8];
#pragma unroll
    for (int i = 0; i < 8; ++i) m8[i] = fmaxf(p[i], p[i + 8]);
    float tm = fmaxf(fmaxf(fmaxf(m8[0], m8[4]), fmaxf(m8[1], m8[5])),
                     fmaxf(fmaxf(m8[2], m8[6]), fmaxf(m8[3], m8[7])));
    tm = fmaxf(tm, __shfl_xor(tm, 32));
    if (!__all(tm <= mrun + 8.0f)) {   // defer-max (T13)
      const float mn = fmaxf(mrun, tm);
      const float scl = __expf(mrun - mn);
      mrun = mn;
      lrun *= scl;
#pragma unroll
      for (int r = 0; r < 16; ++r) { acc0[r] *= scl; acc1[r] *= scl; }
    }
#pragma unroll
    for (int r = 0; r < 16; ++r) p[r] = __expf(p[r] - mrun);
    float s8[8];
#pragma unroll
    for (int i = 0; i < 8; ++i) s8[i] = p[i] + p[i + 8];
    float rs = ((s8[0] + s8[1]) + (s8[2] + s8[3])) + ((s8[4] + s8[5]) + (s8[6] + s8[7]));
    rs += __shfl_xor(rs, 32);
    lrun += rs;
#pragma unroll
    for (int c = 0; c < 2; ++c) {
      const int c8 = c * 8;
      const int A0 = pk2(p[c8 + 0], p[c8 + 1]);
      const int A1 = pk2(p[c8 + 2], p[c8 + 3]);
      const int B0 = pk2(p[c8 + 4], p[c8 + 5]);
      const int B1 = pk2(p[c8 + 6], p[c8 + 7]);
      const int pA0 = __shfl_xor(A0, 32), pA1 = __shfl_xor(A1, 32);
      const int pB0 = __shfl_xor(B0, 32), pB1 = __shfl_xor(B1, 32);
      i32x4 fi;
      fi[0] = hi ? pB0 : A0;
      fi[1] = hi ? pB1 : A1;
      fi[2] = hi ? B0 : pA0;
      fi[3] = hi ? B1 : pA1;
      const bf16x8 pf = __builtin_bit_cast(bf16x8, fi);
      acc0 = mfma32(Vf[0][c], pf, acc0);
      acc1 = mfma32(Vf[1][c], pf, acc1);
    }
    sl = (sl == 2) ? 0 : sl + 1;
    ss = (ss == 2) ? 0 : ss + 1;
  }
#undef STAGE

  const float inv = 1.0f / lrun;
  bf16* cp = ctx + (size_t)(b * LSEQ + q0 + l31) * DIM + h * HD;
#pragma unroll
  for (int r = 0; r < 16; ++r) {
    const int dr = (r & 3) + 8 * (r >> 2) + 4 * hi;
    cp[dr]      = (bf16)(acc0[r] * inv);
    cp[32 + dr] = (bf16)(acc1[r] * inv);
  }
}

// ---------------- launcher ----------------
extern "C" void kernel_launch(void* const* d_in, const int* in_sizes, int n_in,
                              void* d_out, int out_size, void* d_ws, size_t ws_size,
                              hipStream_t stream) {
  const float* x  = (const float*)d_in[0];
  const float* ab = (const float*)d_in[1];
  const float* Wq = (const float*)d_in[2];  const float* bq = (const float*)d_in[3];
  const float* Aq = (const float*)d_in[4];  const float* Bq = (const float*)d_in[5];
  const float* Wk = (const float*)d_in[6];  const float* bk = (const float*)d_in[7];
  const float* Ak = (const float*)d_in[8];  const float* Bk = (const float*)d_in[9];
  const float* Wv = (const float*)d_in[10]; const float* bv = (const float*)d_in[11];
  const float* Av = (const float*)d_in[12]; const float* Bv = (const float*)d_in[13];
  const float* Wo = (const float*)d_in[14]; const float* bo = (const float*)d_in[15];
  const float* Ao = (const float*)d_in[16]; const float* Bo = (const float*)d_in[17];

  uint8_t* ws = (uint8_t*)d_ws;
  const size_t SZ = (size_t)NTOK * DIM * sizeof(bf16);  // 8 MiB
  bf16* xb   = (bf16*)(ws + 0 * SZ);
  bf16* weff = (bf16*)(ws + 1 * SZ);
  bf16* qb   = (bf16*)(ws + 2 * SZ);
  bf16* kb   = (bf16*)(ws + 3 * SZ);
  bf16* vb   = (bf16*)(ws + 4 * SZ);
  bf16* kfb  = (bf16*)(ws + 5 * SZ);
  bf16* vfb  = (bf16*)(ws + 6 * SZ);
  bf16* ctx  = (bf16*)(ws + 7 * SZ);

  k_cvt<<<dim3(NTOK * DIM / 1024), 256, 0, stream>>>(x, xb);

  WeffArgs wa;
  wa.W[0] = Wq; wa.A[0] = Aq; wa.B[0] = Bq; wa.out[0] = weff;
  wa.W[1] = Wk; wa.A[1] = Ak; wa.B[1] = Bk; wa.out[1] = weff + (size_t)DIM * DIM;
  wa.W[2] = Wv; wa.A[2] = Av; wa.B[2] = Bv; wa.out[2] = weff + 2 * (size_t)DIM * DIM;
  wa.W[3] = Wo; wa.A[3] = Ao; wa.B[3] = Bo; wa.out[3] = weff + 3 * (size_t)DIM * DIM;
  k_weff<<<dim3(DIM, 4), 256, 0, stream>>>(wa);

  k_gemm_qkv<<<dim3(32, 8, 3), 256, 0, stream>>>(xb, weff, bq, bk, bv, qb, kb, vb);
  k_vfrag<<<dim3(32, 32), 256, 0, stream>>>(vb, kb, vfb, kfb);
  k_attn<<<dim3(32, 16), 256, 0, stream>>>(qb, kfb, vfb, ab, ctx);
  k_gemm_o<<<dim3(32, 16), 256, 0, stream>>>(ctx, weff + 3 * (size_t)DIM * DIM, bo,
                                             (float*)d_out);
}

// Round 9
// 183.175 us; speedup vs baseline: 2.8891x; 1.0013x over previous
//
#include <hip/hip_runtime.h>
#include <cstdint>

typedef __bf16 bf16;
typedef __bf16 bf16x8 __attribute__((ext_vector_type(8)));
typedef __bf16 bf16x4 __attribute__((ext_vector_type(4)));
typedef float  f32x4  __attribute__((ext_vector_type(4)));
typedef float  f32x16 __attribute__((ext_vector_type(16)));
typedef int    i32x4  __attribute__((ext_vector_type(4)));

#define DIM   1024
#define LSEQ  2048
#define NH    16
#define HD    64
#define NTOK  4096

#define AS1C(p) ((const __attribute__((address_space(1))) void*)(unsigned long long)(uintptr_t)(p))
#define AS3P(p) ((__attribute__((address_space(3))) void*)(unsigned int)(uintptr_t)(p))
#define SB0 __builtin_amdgcn_sched_barrier(0)

__device__ __forceinline__ f32x4 mfma16(bf16x8 a, bf16x8 b, f32x4 c) {
  return __builtin_amdgcn_mfma_f32_16x16x32_bf16(a, b, c, 0, 0, 0);
}
__device__ __forceinline__ f32x16 mfma32(bf16x8 a, bf16x8 b, f32x16 c) {
  return __builtin_amdgcn_mfma_f32_32x32x16_bf16(a, b, c, 0, 0, 0);
}
__device__ __forceinline__ int pk2(float a, float b) {
  unsigned short ua = __builtin_bit_cast(unsigned short, (bf16)a);
  unsigned short ub = __builtin_bit_cast(unsigned short, (bf16)b);
  return (int)ua | ((int)ub << 16);
}

// ---------------- x (fp32) -> bf16 ----------------
__global__ __launch_bounds__(256) void k_cvt(const float* __restrict__ x,
                                             bf16* __restrict__ xb) {
  const int i = (blockIdx.x * 256 + threadIdx.x) * 4;
  const f32x4 v = *(const f32x4*)(x + i);
  bf16x4 o;
  o[0] = (bf16)v[0]; o[1] = (bf16)v[1]; o[2] = (bf16)v[2]; o[3] = (bf16)v[3];
  *(bf16x4*)(xb + i) = o;
}

// ---------------- W_eff[o][d] = W[o][d] + 0.5 * sum_r A[d][r] * B[r][o] ----------------
struct WeffArgs {
  const float* W[4]; const float* A[4]; const float* B[4]; bf16* out[4];
};

__global__ __launch_bounds__(256) void k_weff(WeffArgs args) {
  const int o = blockIdx.x;
  const int z = blockIdx.y;
  const float* __restrict__ W  = args.W[z];
  const float* __restrict__ A  = args.A[z];
  const float* __restrict__ Bm = args.B[z];
  bf16* __restrict__ out = args.out[z];
  float Bo[16];
#pragma unroll
  for (int r = 0; r < 16; ++r) Bo[r] = Bm[r * DIM + o];
#pragma unroll
  for (int j = 0; j < 4; ++j) {
    const int d = j * 256 + (int)threadIdx.x;
    const float* Ar = A + (size_t)d * 16;
    float acc = 0.f;
#pragma unroll
    for (int r = 0; r < 16; ++r) acc += Ar[r] * Bo[r];
    out[(size_t)o * DIM + d] = (bf16)(W[(size_t)o * DIM + d] + 0.5f * acc);
  }
}

// ---------------- GEMM (m97 structure), BN = NF*32 ----------------
template <int NF, bool F32OUT>
__device__ __forceinline__ void gemm_body(const bf16* __restrict__ X,
                                          const bf16* __restrict__ W,
                                          const float* __restrict__ bias,
                                          void* __restrict__ out,
                                          float scale, int m0, int n0) {
  constexpr int BN = NF * 32;
  __shared__ __align__(16) bf16 As[128 * 32];
  __shared__ __align__(16) bf16 Bs[BN * 32];
  const int tid  = threadIdx.x;
  const int lane = tid & 63, w = tid >> 6;
  const int l15 = lane & 15, l4 = lane >> 4;
  const int wr = w >> 1, wc = w & 1;
  const int srow = w * 16 + (lane >> 2);
  const int scol = (lane & 3) * 8;

  f32x4 acc[4][NF] = {};
  const bf16* ag = X + (size_t)m0 * DIM;
  const bf16* bg = W + (size_t)n0 * DIM;

  for (int kt = 0; kt < DIM / 32; ++kt) {
    const int k0 = kt * 32;
#pragma unroll
    for (int j = 0; j < 2; ++j) {
      const int row = j * 64 + srow;
      __builtin_amdgcn_global_load_lds(AS1C(ag + (size_t)row * DIM + k0 + scol),
                                       AS3P(As + (j * 64 + w * 16) * 32), 16, 0, 0);
      if (j * 64 < BN)
        __builtin_amdgcn_global_load_lds(AS1C(bg + (size_t)row * DIM + k0 + scol),
                                         AS3P(Bs + (j * 64 + w * 16) * 32), 16, 0, 0);
    }
    __syncthreads();
    bf16x8 af[4], bfr[NF];
#pragma unroll
    for (int m = 0; m < 4; ++m)
      af[m] = *(const bf16x8*)(As + (wr * 64 + m * 16 + l15) * 32 + l4 * 8);
#pragma unroll
    for (int n = 0; n < NF; ++n)
      bfr[n] = *(const bf16x8*)(Bs + (wc * NF * 16 + n * 16 + l15) * 32 + l4 * 8);
#pragma unroll
    for (int m = 0; m < 4; ++m)
#pragma unroll
      for (int n = 0; n < NF; ++n)
        acc[m][n] = mfma16(af[m], bfr[n], acc[m][n]);
    __syncthreads();
  }

#pragma unroll
  for (int m = 0; m < 4; ++m) {
    const int r0 = m0 + wr * 64 + m * 16 + l4 * 4;
#pragma unroll
    for (int n = 0; n < NF; ++n) {
      const int c = n0 + wc * NF * 16 + n * 16 + l15;
      const float bc = bias[c];
#pragma unroll
      for (int t = 0; t < 4; ++t) {
        const float y = (acc[m][n][t] + bc) * scale;
        if constexpr (F32OUT)
          ((float*)out)[(size_t)(r0 + t) * DIM + c] = y;
        else
          ((bf16*)out)[(size_t)(r0 + t) * DIM + c] = (bf16)y;
      }
    }
  }
}

__global__ __launch_bounds__(256) void k_gemm_qkv(
    const bf16* __restrict__ xb, const bf16* __restrict__ weff,
    const float* __restrict__ bq, const float* __restrict__ bk,
    const float* __restrict__ bv,
    bf16* __restrict__ q, bf16* __restrict__ k, bf16* __restrict__ v) {
  const int z = blockIdx.z;
  const bf16* W = weff + (size_t)z * DIM * DIM;
  const float* bias = (z == 0) ? bq : (z == 1) ? bk : bv;
  bf16* out = (z == 0) ? q : (z == 1) ? k : v;
  const float scale = (z == 0) ? 0.125f : 1.0f;
  gemm_body<4, false>(xb, W, bias, out, scale, blockIdx.x * 128, blockIdx.y * 128);
}

__global__ __launch_bounds__(256) void k_gemm_o(
    const bf16* __restrict__ ctx, const bf16* __restrict__ weffo,
    const float* __restrict__ bo, float* __restrict__ out) {
  gemm_body<2, true>(ctx, weffo, bo, out, 1.0f, blockIdx.x * 128, blockIdx.y * 64);
}

// ---------------- K/V fragment pre-pass ----------------
// kf[bh][t][c][lane] (bf16x8): K[t*32+l31][h*64 + c*16 + hi*8 + j]
// vf[bh][t][n*2+c][lane]     : V^T[n*32+l31][t*32 + c*16 + hi*8 + j]
__global__ __launch_bounds__(256) void k_vfrag(const bf16* __restrict__ v,
                                               const bf16* __restrict__ k,
                                               bf16* __restrict__ vf,
                                               bf16* __restrict__ kf) {
  const int lt = blockIdx.x, bh = blockIdx.y;
  const int b = bh >> 4, h = bh & 15;
  __shared__ __align__(16) bf16 tile[64][72];
  const int tid = threadIdx.x;
  const int r = tid >> 2, c0 = (tid & 3) * 16;
  const bf16* src = v + (size_t)(b * LSEQ + lt * 64) * DIM + h * HD;
  *(bf16x8*)(&tile[r][c0])     = *(const bf16x8*)(src + (size_t)r * DIM + c0);
  *(bf16x8*)(&tile[r][c0 + 8]) = *(const bf16x8*)(src + (size_t)r * DIM + c0 + 8);
  __syncthreads();
  const int w = tid >> 6, lane = tid & 63, l31 = lane & 31, hi = lane >> 5;
  {
    const int tt = w >> 1, n = w & 1;
    const int t = lt * 2 + tt;
#pragma unroll
    for (int c = 0; c < 2; ++c) {
      bf16 tmp[8];
#pragma unroll
      for (int j = 0; j < 8; ++j)
        tmp[j] = tile[tt * 32 + c * 16 + hi * 8 + j][n * 32 + l31];
      *(bf16x8*)(vf + ((((size_t)bh * 64 + t) * 4 + n * 2 + c) * 64 + lane) * 8) =
          *(bf16x8*)tmp;
    }
  }
  {
    const int t = lt * 2 + (w & 1);
    const bf16* krow = k + (size_t)(b * LSEQ + t * 32 + l31) * DIM + h * HD + hi * 8;
#pragma unroll
    for (int cc = 0; cc < 2; ++cc) {
      const int c = (w >> 1) + cc * 2;
      *(bf16x8*)(kf + ((((size_t)bh * 64 + t) * 4 + c) * 64 + lane) * 8) =
          *(const bf16x8*)(krow + c * 16);
    }
  }
}

// ---------------- flash attention: batch-fused v2 (typed arrays) ----------------
// grid (512): h = x&15, q0 = (x>>4)*64. Wave w -> (bb = w>>1, qh = w&1):
// 32 q-rows (q0+qh*32..) of batch bb, full 2048-k walk. Bias staged ONCE per
// block (both batches share it): HBM bias 536 -> 268 MB.
// Staging role (6 glds/wave/step, all arithmetic):
//   K_bb, V_bb element range [qh*1024, qh*1024+1024) ; bias parts bb*2, bb*2+1
//   of q-half qh. Triple-buffer, vmcnt(12), double s_barrier (r6/r7 proven).
__global__ __launch_bounds__(256, 2) void k_attn(
    const bf16* __restrict__ q, const bf16* __restrict__ kf,
    const bf16* __restrict__ vf, const float* __restrict__ bias,
    bf16* __restrict__ ctx) {
  const int tid = threadIdx.x, w = tid >> 6, lane = tid & 63;
  const int l31 = lane & 31, hi = lane >> 5;
  const int bb = w >> 1, qh = w & 1;
  const int h = blockIdx.x & 15;
  const int q0 = (blockIdx.x >> 4) * 64;

  __shared__ __align__(16) bf16  kls[2][3][2048];   // 24 KB
  __shared__ __align__(16) bf16  vls[2][3][2048];   // 24 KB
  __shared__ __align__(16) float bls[2][3][1024];   // 24 KB

  // Q fragment: batch bb, q-rows q0 + qh*32 + l31
  const bf16* qrow = q + (size_t)(bb * LSEQ + q0 + qh * 32 + l31) * DIM + h * HD;
  bf16x8 Qf[4];
#pragma unroll
  for (int c = 0; c < 4; ++c) Qf[c] = *(const bf16x8*)(qrow + c * 16 + hi * 8);

  // staging sources (per-wave arithmetic roles)
  const int part2  = qh * 2;   // K/V quarter pair for batch bb
  const int bpart2 = bb * 2;   // bias part pair for q-half qh
  const int lr = lane >> 3, lc = lane & 7;
  const bf16* ksrc = kf + (size_t)(bb * NH + h) * 64 * 2048 + part2 * 512 + lane * 8;
  const bf16* vsrc = vf + (size_t)(bb * NH + h) * 64 * 2048 + part2 * 512 + lane * 8;
  const float* bsrc =
      bias + ((size_t)h * LSEQ + q0 + qh * 32 + bpart2 * 8 + lr) * LSEQ + 4 * (lc ^ lr);

  f32x16 acc0 = {}, acc1 = {};
  float mrun = -3e38f, lrun = 0.f;

#define STAGE(t_, s_)                                                          \
  {                                                                            \
    __builtin_amdgcn_global_load_lds(AS1C(ksrc + (size_t)(t_) * 2048),         \
                                     AS3P(&kls[bb][s_][part2 * 512]), 16, 0, 0);\
    __builtin_amdgcn_global_load_lds(AS1C(ksrc + (size_t)(t_) * 2048 + 512),   \
                                     AS3P(&kls[bb][s_][part2 * 512 + 512]), 16, 0, 0);\
    __builtin_amdgcn_global_load_lds(AS1C(vsrc + (size_t)(t_) * 2048),         \
                                     AS3P(&vls[bb][s_][part2 * 512]), 16, 0, 0);\
    __builtin_amdgcn_global_load_lds(AS1C(vsrc + (size_t)(t_) * 2048 + 512),   \
                                     AS3P(&vls[bb][s_][part2 * 512 + 512]), 16, 0, 0);\
    __builtin_amdgcn_global_load_lds(AS1C(bsrc + (size_t)(t_) * 32),           \
                                     AS3P(&bls[qh][s_][bpart2 * 256]), 16, 0, 0);\
    __builtin_amdgcn_global_load_lds(AS1C(bsrc + (size_t)(t_) * 32 + 8 * LSEQ),\
                                     AS3P(&bls[qh][s_][bpart2 * 256 + 256]), 16, 0, 0);\
  }

  STAGE(0, 0); SB0;
  STAGE(1, 1); SB0;

  const int sw = (l31 & 7) << 2;
  int sl = 0, ss = 2;  // read slot, stage slot
  for (int t = 0; t < 64; ++t) {
    const int tn = (t + 2 > 63) ? 63 : t + 2;
    STAGE(tn, ss); SB0;
    asm volatile("s_waitcnt vmcnt(12)" ::: "memory");
    __builtin_amdgcn_s_barrier();   // slot sl fully staged (each wave waited on own)

    bf16x8 Kf[4], Vf[2][2];
    f32x4 br[4];
#pragma unroll
    for (int c = 0; c < 4; ++c)
      Kf[c] = *(const bf16x8*)(&kls[bb][sl][c * 512 + lane * 8]);
#pragma unroll
    for (int u = 0; u < 4; ++u)
      Vf[u >> 1][u & 1] = *(const bf16x8*)(&vls[bb][sl][u * 512 + lane * 8]);
#pragma unroll
    for (int g = 0; g < 4; ++g)
      br[g] = *(const f32x4*)(
          &bls[qh][sl][l31 * 32 + (((g << 3) | (hi << 2)) ^ sw)]);
    asm volatile("s_waitcnt lgkmcnt(0)" ::: "memory");
    SB0;
    __builtin_amdgcn_s_barrier();   // reads done: slot sl may be overwritten

    // ---- compute step t ----
    f32x16 s = {};
#pragma unroll
    for (int c = 0; c < 4; ++c) s = mfma32(Kf[c], Qf[c], s);
    float p[16];
#pragma unroll
    for (int r = 0; r < 16; ++r) p[r] = s[r] + br[r >> 2][r & 3];
    float m8[8];
#pragma unroll
    for (int i = 0; i < 8; ++i) m8[i] = fmaxf(p[i], p[i + 8]);
    float tm = fmaxf(fmaxf(fmaxf(m8[0], m8[4]), fmaxf(m8[1], m8[5])),
                     fmaxf(fmaxf(m8[2], m8[6]), fmaxf(m8[3], m8[7])));
    tm = fmaxf(tm, __shfl_xor(tm, 32));
    if (!__all(tm <= mrun + 8.0f)) {   // defer-max (T13)
      const float mn = fmaxf(mrun, tm);
      const float scl = __expf(mrun - mn);
      mrun = mn;
      lrun *= scl;
#pragma unroll
      for (int r = 0; r < 16; ++r) { acc0[r] *= scl; acc1[r] *= scl; }
    }
#pragma unroll
    for (int r = 0; r < 16; ++r) p[r] = __expf(p[r] - mrun);
    float s8[8];
#pragma unroll
    for (int i = 0; i < 8; ++i) s8[i] = p[i] + p[i + 8];
    float rs = ((s8[0] + s8[1]) + (s8[2] + s8[3])) + ((s8[4] + s8[5]) + (s8[6] + s8[7]));
    rs += __shfl_xor(rs, 32);
    lrun += rs;
#pragma unroll
    for (int c = 0; c < 2; ++c) {
      const int c8 = c * 8;
      const int A0 = pk2(p[c8 + 0], p[c8 + 1]);
      const int A1 = pk2(p[c8 + 2], p[c8 + 3]);
      const int B0 = pk2(p[c8 + 4], p[c8 + 5]);
      const int B1 = pk2(p[c8 + 6], p[c8 + 7]);
      const int pA0 = __shfl_xor(A0, 32), pA1 = __shfl_xor(A1, 32);
      const int pB0 = __shfl_xor(B0, 32), pB1 = __shfl_xor(B1, 32);
      i32x4 fi;
      fi[0] = hi ? pB0 : A0;
      fi[1] = hi ? pB1 : A1;
      fi[2] = hi ? B0 : pA0;
      fi[3] = hi ? B1 : pA1;
      const bf16x8 pf = __builtin_bit_cast(bf16x8, fi);
      acc0 = mfma32(Vf[0][c], pf, acc0);
      acc1 = mfma32(Vf[1][c], pf, acc1);
    }
    sl = (sl == 2) ? 0 : sl + 1;
    ss = (ss == 2) ? 0 : ss + 1;
  }
#undef STAGE

  const float inv = 1.0f / lrun;
  bf16* cp = ctx + (size_t)(bb * LSEQ + q0 + qh * 32 + l31) * DIM + h * HD;
#pragma unroll
  for (int r = 0; r < 16; ++r) {
    const int dr = (r & 3) + 8 * (r >> 2) + 4 * hi;
    cp[dr]      = (bf16)(acc0[r] * inv);
    cp[32 + dr] = (bf16)(acc1[r] * inv);
  }
}

// ---------------- launcher ----------------
extern "C" void kernel_launch(void* const* d_in, const int* in_sizes, int n_in,
                              void* d_out, int out_size, void* d_ws, size_t ws_size,
                              hipStream_t stream) {
  const float* x  = (const float*)d_in[0];
  const float* ab = (const float*)d_in[1];
  const float* Wq = (const float*)d_in[2];  const float* bq = (const float*)d_in[3];
  const float* Aq = (const float*)d_in[4];  const float* Bq = (const float*)d_in[5];
  const float* Wk = (const float*)d_in[6];  const float* bk = (const float*)d_in[7];
  const float* Ak = (const float*)d_in[8];  const float* Bk = (const float*)d_in[9];
  const float* Wv = (const float*)d_in[10]; const float* bv = (const float*)d_in[11];
  const float* Av = (const float*)d_in[12]; const float* Bv = (const float*)d_in[13];
  const float* Wo = (const float*)d_in[14]; const float* bo = (const float*)d_in[15];
  const float* Ao = (const float*)d_in[16]; const float* Bo = (const float*)d_in[17];

  uint8_t* ws = (uint8_t*)d_ws;
  const size_t SZ = (size_t)NTOK * DIM * sizeof(bf16);  // 8 MiB
  bf16* xb   = (bf16*)(ws + 0 * SZ);
  bf16* weff = (bf16*)(ws + 1 * SZ);
  bf16* qb   = (bf16*)(ws + 2 * SZ);
  bf16* kb   = (bf16*)(ws + 3 * SZ);
  bf16* vb   = (bf16*)(ws + 4 * SZ);
  bf16* kfb  = (bf16*)(ws + 5 * SZ);
  bf16* vfb  = (bf16*)(ws + 6 * SZ);
  bf16* ctx  = (bf16*)(ws + 7 * SZ);

  k_cvt<<<dim3(NTOK * DIM / 1024), 256, 0, stream>>>(x, xb);

  WeffArgs wa;
  wa.W[0] = Wq; wa.A[0] = Aq; wa.B[0] = Bq; wa.out[0] = weff;
  wa.W[1] = Wk; wa.A[1] = Ak; wa.B[1] = Bk; wa.out[1] = weff + (size_t)DIM * DIM;
  wa.W[2] = Wv; wa.A[2] = Av; wa.B[2] = Bv; wa.out[2] = weff + 2 * (size_t)DIM * DIM;
  wa.W[3] = Wo; wa.A[3] = Ao; wa.B[3] = Bo; wa.out[3] = weff + 3 * (size_t)DIM * DIM;
  k_weff<<<dim3(DIM, 4), 256, 0, stream>>>(wa);

  k_gemm_qkv<<<dim3(32, 8, 3), 256, 0, stream>>>(xb, weff, bq, bk, bv, qb, kb, vb);
  k_vfrag<<<dim3(32, 32), 256, 0, stream>>>(vb, kb, vfb, kfb);
  k_attn<<<dim3(512), 256, 0, stream>>>(qb, kfb, vfb, ab, ctx);
  k_gemm_o<<<dim3(32, 16), 256, 0, stream>>>(ctx, weff + 3 * (size_t)DIM * DIM, bo,
                                             (float*)d_out);
}

// Round 10
// 172.121 us; speedup vs baseline: 3.0747x; 1.0642x over previous
//
#include <hip/hip_runtime.h>
#include <cstdint>

typedef __bf16 bf16;
typedef __bf16 bf16x8 __attribute__((ext_vector_type(8)));
typedef __bf16 bf16x4 __attribute__((ext_vector_type(4)));
typedef float  f32x4  __attribute__((ext_vector_type(4)));
typedef float  f32x16 __attribute__((ext_vector_type(16)));
typedef int    i32x4  __attribute__((ext_vector_type(4)));

#define DIM   1024
#define LSEQ  2048
#define NH    16
#define HD    64
#define NTOK  4096

#define AS1C(p) ((const __attribute__((address_space(1))) void*)(unsigned long long)(uintptr_t)(p))
#define AS3P(p) ((__attribute__((address_space(3))) void*)(unsigned int)(uintptr_t)(p))
#define SB0 __builtin_amdgcn_sched_barrier(0)

__device__ __forceinline__ f32x4 mfma16(bf16x8 a, bf16x8 b, f32x4 c) {
  return __builtin_amdgcn_mfma_f32_16x16x32_bf16(a, b, c, 0, 0, 0);
}
__device__ __forceinline__ f32x16 mfma32(bf16x8 a, bf16x8 b, f32x16 c) {
  return __builtin_amdgcn_mfma_f32_32x32x16_bf16(a, b, c, 0, 0, 0);
}
__device__ __forceinline__ int pk2(float a, float b) {
  unsigned short ua = __builtin_bit_cast(unsigned short, (bf16)a);
  unsigned short ub = __builtin_bit_cast(unsigned short, (bf16)b);
  return (int)ua | ((int)ub << 16);
}

// ---------------- x (fp32) -> bf16 ----------------
__global__ __launch_bounds__(256) void k_cvt(const float* __restrict__ x,
                                             bf16* __restrict__ xb) {
  const int i = (blockIdx.x * 256 + threadIdx.x) * 4;
  const f32x4 v = *(const f32x4*)(x + i);
  bf16x4 o;
  o[0] = (bf16)v[0]; o[1] = (bf16)v[1]; o[2] = (bf16)v[2]; o[3] = (bf16)v[3];
  *(bf16x4*)(xb + i) = o;
}

// ---------------- W_eff[o][d] = W[o][d] + 0.5 * sum_r A[d][r] * B[r][o] ----------------
struct WeffArgs {
  const float* W[4]; const float* A[4]; const float* B[4]; bf16* out[4];
};

__global__ __launch_bounds__(256) void k_weff(WeffArgs args) {
  const int o = blockIdx.x;
  const int z = blockIdx.y;
  const float* __restrict__ W  = args.W[z];
  const float* __restrict__ A  = args.A[z];
  const float* __restrict__ Bm = args.B[z];
  bf16* __restrict__ out = args.out[z];
  float Bo[16];
#pragma unroll
  for (int r = 0; r < 16; ++r) Bo[r] = Bm[r * DIM + o];
#pragma unroll
  for (int j = 0; j < 4; ++j) {
    const int d = j * 256 + (int)threadIdx.x;
    const float* Ar = A + (size_t)d * 16;
    float acc = 0.f;
#pragma unroll
    for (int r = 0; r < 16; ++r) acc += Ar[r] * Bo[r];
    out[(size_t)o * DIM + d] = (bf16)(W[(size_t)o * DIM + d] + 0.5f * acc);
  }
}

// ---------------- GEMM (m97 structure), BN = NF*32 ----------------
template <int NF, bool F32OUT>
__device__ __forceinline__ void gemm_body(const bf16* __restrict__ X,
                                          const bf16* __restrict__ W,
                                          const float* __restrict__ bias,
                                          void* __restrict__ out,
                                          float scale, int m0, int n0) {
  constexpr int BN = NF * 32;
  __shared__ __align__(16) bf16 As[128 * 32];
  __shared__ __align__(16) bf16 Bs[BN * 32];
  const int tid  = threadIdx.x;
  const int lane = tid & 63, w = tid >> 6;
  const int l15 = lane & 15, l4 = lane >> 4;
  const int wr = w >> 1, wc = w & 1;
  const int srow = w * 16 + (lane >> 2);
  const int scol = (lane & 3) * 8;

  f32x4 acc[4][NF] = {};
  const bf16* ag = X + (size_t)m0 * DIM;
  const bf16* bg = W + (size_t)n0 * DIM;

  for (int kt = 0; kt < DIM / 32; ++kt) {
    const int k0 = kt * 32;
#pragma unroll
    for (int j = 0; j < 2; ++j) {
      const int row = j * 64 + srow;
      __builtin_amdgcn_global_load_lds(AS1C(ag + (size_t)row * DIM + k0 + scol),
                                       AS3P(As + (j * 64 + w * 16) * 32), 16, 0, 0);
      if (j * 64 < BN)
        __builtin_amdgcn_global_load_lds(AS1C(bg + (size_t)row * DIM + k0 + scol),
                                         AS3P(Bs + (j * 64 + w * 16) * 32), 16, 0, 0);
    }
    __syncthreads();
    bf16x8 af[4], bfr[NF];
#pragma unroll
    for (int m = 0; m < 4; ++m)
      af[m] = *(const bf16x8*)(As + (wr * 64 + m * 16 + l15) * 32 + l4 * 8);
#pragma unroll
    for (int n = 0; n < NF; ++n)
      bfr[n] = *(const bf16x8*)(Bs + (wc * NF * 16 + n * 16 + l15) * 32 + l4 * 8);
#pragma unroll
    for (int m = 0; m < 4; ++m)
#pragma unroll
      for (int n = 0; n < NF; ++n)
        acc[m][n] = mfma16(af[m], bfr[n], acc[m][n]);
    __syncthreads();
  }

#pragma unroll
  for (int m = 0; m < 4; ++m) {
    const int r0 = m0 + wr * 64 + m * 16 + l4 * 4;
#pragma unroll
    for (int n = 0; n < NF; ++n) {
      const int c = n0 + wc * NF * 16 + n * 16 + l15;
      const float bc = bias[c];
#pragma unroll
      for (int t = 0; t < 4; ++t) {
        const float y = (acc[m][n][t] + bc) * scale;
        if constexpr (F32OUT)
          ((float*)out)[(size_t)(r0 + t) * DIM + c] = y;
        else
          ((bf16*)out)[(size_t)(r0 + t) * DIM + c] = (bf16)y;
      }
    }
  }
}

__global__ __launch_bounds__(256) void k_gemm_qkv(
    const bf16* __restrict__ xb, const bf16* __restrict__ weff,
    const float* __restrict__ bq, const float* __restrict__ bk,
    const float* __restrict__ bv,
    bf16* __restrict__ q, bf16* __restrict__ k, bf16* __restrict__ v) {
  const int z = blockIdx.z;
  const bf16* W = weff + (size_t)z * DIM * DIM;
  const float* bias = (z == 0) ? bq : (z == 1) ? bk : bv;
  bf16* out = (z == 0) ? q : (z == 1) ? k : v;
  const float scale = (z == 0) ? 0.125f : 1.0f;
  gemm_body<4, false>(xb, W, bias, out, scale, blockIdx.x * 128, blockIdx.y * 128);
}

__global__ __launch_bounds__(256) void k_gemm_o(
    const bf16* __restrict__ ctx, const bf16* __restrict__ weffo,
    const float* __restrict__ bo, float* __restrict__ out) {
  gemm_body<2, true>(ctx, weffo, bo, out, 1.0f, blockIdx.x * 128, blockIdx.y * 64);
}

// ---------------- K/V fragment pre-pass ----------------
// kf[bh][t][c][lane] (bf16x8): K[t*32+l31][h*64 + c*16 + hi*8 + j]
// vf[bh][t][n*2+c][lane]     : V^T[n*32+l31][t*32 + c*16 + hi*8 + j]
__global__ __launch_bounds__(256) void k_vfrag(const bf16* __restrict__ v,
                                               const bf16* __restrict__ k,
                                               bf16* __restrict__ vf,
                                               bf16* __restrict__ kf) {
  const int lt = blockIdx.x, bh = blockIdx.y;
  const int b = bh >> 4, h = bh & 15;
  __shared__ __align__(16) bf16 tile[64][72];
  const int tid = threadIdx.x;
  const int r = tid >> 2, c0 = (tid & 3) * 16;
  const bf16* src = v + (size_t)(b * LSEQ + lt * 64) * DIM + h * HD;
  *(bf16x8*)(&tile[r][c0])     = *(const bf16x8*)(src + (size_t)r * DIM + c0);
  *(bf16x8*)(&tile[r][c0 + 8]) = *(const bf16x8*)(src + (size_t)r * DIM + c0 + 8);
  __syncthreads();
  const int w = tid >> 6, lane = tid & 63, l31 = lane & 31, hi = lane >> 5;
  {
    const int tt = w >> 1, n = w & 1;
    const int t = lt * 2 + tt;
#pragma unroll
    for (int c = 0; c < 2; ++c) {
      bf16 tmp[8];
#pragma unroll
      for (int j = 0; j < 8; ++j)
        tmp[j] = tile[tt * 32 + c * 16 + hi * 8 + j][n * 32 + l31];
      *(bf16x8*)(vf + ((((size_t)bh * 64 + t) * 4 + n * 2 + c) * 64 + lane) * 8) =
          *(bf16x8*)tmp;
    }
  }
  {
    const int t = lt * 2 + (w & 1);
    const bf16* krow = k + (size_t)(b * LSEQ + t * 32 + l31) * DIM + h * HD + hi * 8;
#pragma unroll
    for (int cc = 0; cc < 2; ++cc) {
      const int c = (w >> 1) + cc * 2;
      *(bf16x8*)(kf + ((((size_t)bh * 64 + t) * 4 + c) * 64 + lane) * 8) =
          *(const bf16x8*)(krow + c * 16);
    }
  }
}

// ---------------- flash attention v3: 512-thread block, feed-amortized ----------------
// grid (256): h = x&15, q0 = (x>>4)*128. 8 waves, wave -> (bb = w>>2, qs = w&3):
// 32 q-rows (q0+qs*32) of batch bb, full 2048-k walk. Per step staged: K/V both
// batches (16KB) + bias 128 rows (16KB, batch-shared) = 32KB serving 256 q-rows
// (1.5x feed efficiency vs r9's 48KB/128rows; K/V re-read total 512->256 MB).
// 4 glds/wave/step, triple-buffer, vmcnt(8), double s_barrier. LDS 96KB, 1 blk/CU.
__global__ __launch_bounds__(512, 2) void k_attn(
    const bf16* __restrict__ q, const bf16* __restrict__ kf,
    const bf16* __restrict__ vf, const float* __restrict__ bias,
    bf16* __restrict__ ctx) {
  const int tid = threadIdx.x, w = tid >> 6, lane = tid & 63;
  const int l31 = lane & 31, hi = lane >> 5;
  const int bb = w >> 2, qs = w & 3;
  const int h = blockIdx.x & 15;
  const int q0 = (blockIdx.x >> 4) * 128;

  __shared__ __align__(16) bf16  kls[2][3][2048];   // 24 KB
  __shared__ __align__(16) bf16  vls[2][3][2048];   // 24 KB
  __shared__ __align__(16) float bls[3][4096];      // 48 KB (128 rows x 32 cols)

  // Q fragment: batch bb, q-rows q0 + qs*32 + l31
  const bf16* qrow = q + (size_t)(bb * LSEQ + q0 + qs * 32 + l31) * DIM + h * HD;
  bf16x8 Qf[4];
#pragma unroll
  for (int c = 0; c < 4; ++c) Qf[c] = *(const bf16x8*)(qrow + c * 16 + hi * 8);

  // ---- staging roles: wave w stages KV ids {2w,2w+1} and bias blocks {2w,2w+1}
  // KV id kv in 0..15: batch = kv>>3, V? = (kv>>2)&1, quarter c = kv&3.
  const int kvA = 2 * w, kvB = 2 * w + 1;
  const int kbA = kvA >> 3, vvA = (kvA >> 2) & 1, cA = kvA & 3;
  const int kbB = kvB >> 3, vvB = (kvB >> 2) & 1, cB = kvB & 3;
  const bf16* srcA = (vvA ? vf : kf) + (size_t)(kbA * NH + h) * 64 * 2048 + cA * 512 + lane * 8;
  const bf16* srcB = (vvB ? vf : kf) + (size_t)(kbB * NH + h) * 64 * 2048 + cB * 512 + lane * 8;
  bf16* dstA = (vvA ? &vls[kbA][0][0] : &kls[kbA][0][0]) + cA * 512 + lane * 8;
  bf16* dstB = (vvB ? &vls[kbB][0][0] : &kls[kbB][0][0]) + cB * 512 + lane * 8;
  // bias glds 2w, 2w+1: 8 rows each (rows q0+16w.. and q0+16w+8..), swizzled col
  const int lr = lane >> 3, lc = lane & 7;
  const float* bsA = bias + ((size_t)h * LSEQ + q0 + 16 * w + lr) * LSEQ + 4 * (lc ^ lr);
  const float* bsB = bsA + (size_t)8 * LSEQ;
  float* bdA = &bls[0][0] + (2 * w) * 256 + lane * 4;
  float* bdB = bdA + 256;

  f32x16 acc0 = {}, acc1 = {};
  float mrun = -3e38f, lrun = 0.f;

#define STAGE(t_, s_)                                                          \
  {                                                                            \
    __builtin_amdgcn_global_load_lds(AS1C(srcA + (size_t)(t_) * 2048),         \
                                     AS3P(dstA + (s_) * 2048), 16, 0, 0);      \
    __builtin_amdgcn_global_load_lds(AS1C(srcB + (size_t)(t_) * 2048),         \
                                     AS3P(dstB + (s_) * 2048), 16, 0, 0);      \
    __builtin_amdgcn_global_load_lds(AS1C(bsA + (size_t)(t_) * 32),            \
                                     AS3P(bdA + (s_) * 4096), 16, 0, 0);       \
    __builtin_amdgcn_global_load_lds(AS1C(bsB + (size_t)(t_) * 32),            \
                                     AS3P(bdB + (s_) * 4096), 16, 0, 0);       \
  }

  STAGE(0, 0); SB0;
  STAGE(1, 1); SB0;

  const int rr = qs * 32 + l31;          // bias row within block
  const int sw = (l31 & 7) << 2;
  int sl = 0, ss = 2;  // read slot, stage slot
  for (int t = 0; t < 64; ++t) {
    const int tn = (t + 2 > 63) ? 63 : t + 2;
    STAGE(tn, ss); SB0;
    asm volatile("s_waitcnt vmcnt(8)" ::: "memory");
    __builtin_amdgcn_s_barrier();   // slot sl fully staged (each wave waited on own)

    bf16x8 Kf[4], Vf[2][2];
    f32x4 br[4];
#pragma unroll
    for (int c = 0; c < 4; ++c)
      Kf[c] = *(const bf16x8*)(&kls[bb][sl][c * 512 + lane * 8]);
#pragma unroll
    for (int u = 0; u < 4; ++u)
      Vf[u >> 1][u & 1] = *(const bf16x8*)(&vls[bb][sl][u * 512 + lane * 8]);
#pragma unroll
    for (int g = 0; g < 4; ++g)
      br[g] = *(const f32x4*)(
          &bls[sl][rr * 32 + (((g << 3) | (hi << 2)) ^ sw)]);
    asm volatile("s_waitcnt lgkmcnt(0)" ::: "memory");
    SB0;
    __builtin_amdgcn_s_barrier();   // reads done: slot sl may be overwritten

    // ---- compute step t ----
    f32x16 s = {};
#pragma unroll
    for (int c = 0; c < 4; ++c) s = mfma32(Kf[c], Qf[c], s);
    float p[16];
#pragma unroll
    for (int r = 0; r < 16; ++r) p[r] = s[r] + br[r >> 2][r & 3];
    float m8[8];
#pragma unroll
    for (int i = 0; i < 8; ++i) m8[i] = fmaxf(p[i], p[i + 8]);
    float tm = fmaxf(fmaxf(fmaxf(m8[0], m8[4]), fmaxf(m8[1], m8[5])),
                     fmaxf(fmaxf(m8[2], m8[6]), fmaxf(m8[3], m8[7])));
    tm = fmaxf(tm, __shfl_xor(tm, 32));
    if (!__all(tm <= mrun + 8.0f)) {   // defer-max (T13)
      const float mn = fmaxf(mrun, tm);
      const float scl = __expf(mrun - mn);
      mrun = mn;
      lrun *= scl;
#pragma unroll
      for (int r = 0; r < 16; ++r) { acc0[r] *= scl; acc1[r] *= scl; }
    }
#pragma unroll
    for (int r = 0; r < 16; ++r) p[r] = __expf(p[r] - mrun);
    float s8[8];
#pragma unroll
    for (int i = 0; i < 8; ++i) s8[i] = p[i] + p[i + 8];
    float rs = ((s8[0] + s8[1]) + (s8[2] + s8[3])) + ((s8[4] + s8[5]) + (s8[6] + s8[7]));
    rs += __shfl_xor(rs, 32);
    lrun += rs;
#pragma unroll
    for (int c = 0; c < 2; ++c) {
      const int c8 = c * 8;
      const int A0 = pk2(p[c8 + 0], p[c8 + 1]);
      const int A1 = pk2(p[c8 + 2], p[c8 + 3]);
      const int B0 = pk2(p[c8 + 4], p[c8 + 5]);
      const int B1 = pk2(p[c8 + 6], p[c8 + 7]);
      const int pA0 = __shfl_xor(A0, 32), pA1 = __shfl_xor(A1, 32);
      const int pB0 = __shfl_xor(B0, 32), pB1 = __shfl_xor(B1, 32);
      i32x4 fi;
      fi[0] = hi ? pB0 : A0;
      fi[1] = hi ? pB1 : A1;
      fi[2] = hi ? B0 : pA0;
      fi[3] = hi ? B1 : pA1;
      const bf16x8 pf = __builtin_bit_cast(bf16x8, fi);
      acc0 = mfma32(Vf[0][c], pf, acc0);
      acc1 = mfma32(Vf[1][c], pf, acc1);
    }
    sl = (sl == 2) ? 0 : sl + 1;
    ss = (ss == 2) ? 0 : ss + 1;
  }
#undef STAGE

  const float inv = 1.0f / lrun;
  bf16* cp = ctx + (size_t)(bb * LSEQ + q0 + qs * 32 + l31) * DIM + h * HD;
#pragma unroll
  for (int r = 0; r < 16; ++r) {
    const int dr = (r & 3) + 8 * (r >> 2) + 4 * hi;
    cp[dr]      = (bf16)(acc0[r] * inv);
    cp[32 + dr] = (bf16)(acc1[r] * inv);
  }
}

// ---------------- launcher ----------------
extern "C" void kernel_launch(void* const* d_in, const int* in_sizes, int n_in,
                              void* d_out, int out_size, void* d_ws, size_t ws_size,
                              hipStream_t stream) {
  const float* x  = (const float*)d_in[0];
  const float* ab = (const float*)d_in[1];
  const float* Wq = (const float*)d_in[2];  const float* bq = (const float*)d_in[3];
  const float* Aq = (const float*)d_in[4];  const float* Bq = (const float*)d_in[5];
  const float* Wk = (const float*)d_in[6];  const float* bk = (const float*)d_in[7];
  const float* Ak = (const float*)d_in[8];  const float* Bk = (const float*)d_in[9];
  const float* Wv = (const float*)d_in[10]; const float* bv = (const float*)d_in[11];
  const float* Av = (const float*)d_in[12]; const float* Bv = (const float*)d_in[13];
  const float* Wo = (const float*)d_in[14]; const float* bo = (const float*)d_in[15];
  const float* Ao = (const float*)d_in[16]; const float* Bo = (const float*)d_in[17];

  uint8_t* ws = (uint8_t*)d_ws;
  const size_t SZ = (size_t)NTOK * DIM * sizeof(bf16);  // 8 MiB
  bf16* xb   = (bf16*)(ws + 0 * SZ);
  bf16* weff = (bf16*)(ws + 1 * SZ);
  bf16* qb   = (bf16*)(ws + 2 * SZ);
  bf16* kb   = (bf16*)(ws + 3 * SZ);
  bf16* vb   = (bf16*)(ws + 4 * SZ);
  bf16* kfb  = (bf16*)(ws + 5 * SZ);
  bf16* vfb  = (bf16*)(ws + 6 * SZ);
  bf16* ctx  = (bf16*)(ws + 7 * SZ);

  k_cvt<<<dim3(NTOK * DIM / 1024), 256, 0, stream>>>(x, xb);

  WeffArgs wa;
  wa.W[0] = Wq; wa.A[0] = Aq; wa.B[0] = Bq; wa.out[0] = weff;
  wa.W[1] = Wk; wa.A[1] = Ak; wa.B[1] = Bk; wa.out[1] = weff + (size_t)DIM * DIM;
  wa.W[2] = Wv; wa.A[2] = Av; wa.B[2] = Bv; wa.out[2] = weff + 2 * (size_t)DIM * DIM;
  wa.W[3] = Wo; wa.A[3] = Ao; wa.B[3] = Bo; wa.out[3] = weff + 3 * (size_t)DIM * DIM;
  k_weff<<<dim3(DIM, 4), 256, 0, stream>>>(wa);

  k_gemm_qkv<<<dim3(32, 8, 3), 256, 0, stream>>>(xb, weff, bq, bk, bv, qb, kb, vb);
  k_vfrag<<<dim3(32, 32), 256, 0, stream>>>(vb, kb, vfb, kfb);
  k_attn<<<dim3(256), 512, 0, stream>>>(qb, kfb, vfb, ab, ctx);
  k_gemm_o<<<dim3(32, 16), 256, 0, stream>>>(ctx, weff + 3 * (size_t)DIM * DIM, bo,
                                             (float*)d_out);
}